// Round 1
// baseline (953.399 us; speedup 1.0000x reference)
//
#include <hip/hip_runtime.h>
#include <math.h>
#include <stdint.h>

#define NND  100000   // nodes
#define NED  1600000  // edges (without self loops)
#define FIN  512
#define HID  128
#define ENC  64
#define NCLS 10
#define DOM  40

#define SCAN_BS 256
#define NBS ((NND + SCAN_BS - 1) / SCAN_BS)   // 391

// ---------------- degree / norm ----------------

__global__ void k_deg(const int* __restrict__ dst, const float* __restrict__ ppmi,
                      int* __restrict__ deg_cnt, float* __restrict__ degp) {
  int e = blockIdx.x * blockDim.x + threadIdx.x;
  if (e >= NED) return;
  int d = dst[e];
  atomicAdd(&deg_cnt[d], 1);
  atomicAdd(&degp[d], ppmi[e]);
}

__global__ void k_dinv(const int* __restrict__ deg_cnt, const float* __restrict__ degp,
                       float* __restrict__ dinv_g, float* __restrict__ dinv_p) {
  int i = blockIdx.x * blockDim.x + threadIdx.x;
  if (i >= NND) return;
  // self-loop contributes +1 to both degree sums; deg > 0 always
  dinv_g[i] = 1.0f / sqrtf((float)deg_cnt[i] + 1.0f);
  dinv_p[i] = 1.0f / sqrtf(degp[i] + 1.0f);
}

// ---------------- 3-kernel exclusive scan (row_ptr) ----------------

__global__ void k_scan_a(const int* __restrict__ deg, int* __restrict__ psum) {
  __shared__ int s[SCAN_BS];
  int t = threadIdx.x, i = blockIdx.x * SCAN_BS + t;
  s[t] = (i < NND) ? deg[i] : 0;
  __syncthreads();
  for (int o = SCAN_BS / 2; o; o >>= 1) {
    if (t < o) s[t] += s[t + o];
    __syncthreads();
  }
  if (t == 0) psum[blockIdx.x] = s[0];
}

__global__ void k_scan_b(int* __restrict__ psum) {
  __shared__ int s[512];
  int t = threadIdx.x;
  int v = (t < NBS) ? psum[t] : 0;
  s[t] = v;
  __syncthreads();
  for (int o = 1; o < 512; o <<= 1) {
    int add = (t >= o) ? s[t - o] : 0;
    __syncthreads();
    s[t] += add;
    __syncthreads();
  }
  if (t < NBS) psum[t] = s[t] - v;   // exclusive
}

__global__ void k_scan_c(const int* __restrict__ deg, const int* __restrict__ psum,
                         int* __restrict__ row_ptr) {
  __shared__ int s[SCAN_BS];
  int t = threadIdx.x, i = blockIdx.x * SCAN_BS + t;
  int v = (i < NND) ? deg[i] : 0;
  s[t] = v;
  __syncthreads();
  for (int o = 1; o < SCAN_BS; o <<= 1) {
    int add = (t >= o) ? s[t - o] : 0;
    __syncthreads();
    s[t] += add;
    __syncthreads();
  }
  if (i < NND) row_ptr[i] = psum[blockIdx.x] + s[t] - v;
  if (i == NND - 1) row_ptr[NND] = psum[blockIdx.x] + s[t];  // == NED
}

// ---------------- CSR scatter (stores both edge norms) ----------------

__global__ void k_scatter(const int* __restrict__ src, const int* __restrict__ dst,
                          const float* __restrict__ ppmi,
                          const int* __restrict__ row_ptr, int* __restrict__ cursor,
                          const float* __restrict__ dinv_g, const float* __restrict__ dinv_p,
                          int* __restrict__ csr_src, float* __restrict__ csr_gn,
                          float* __restrict__ csr_pn) {
  int e = blockIdx.x * blockDim.x + threadIdx.x;
  if (e >= NED) return;
  int s = src[e], d = dst[e];
  int pos = row_ptr[d] + atomicAdd(&cursor[d], 1);
  csr_src[pos] = s;
  csr_gn[pos] = dinv_g[s] * dinv_g[d];
  csr_pn[pos] = dinv_p[s] * ppmi[e] * dinv_p[d];
}

// ---------------- fp32 SGEMM: C[M,Nc] = A[M,K] @ B[K,Nc] ----------------
// 64x64 tile, BK=16, 256 threads, 4x4 per thread. K%16==0, Nc%64==0, M ragged.

__global__ __launch_bounds__(256) void sgemm(const float* __restrict__ A,
                                             const float* __restrict__ B,
                                             float* __restrict__ C,
                                             int M, int K, int Nc) {
  __shared__ float As[16][64];
  __shared__ float Bs[16][64];
  const int tid = threadIdx.x;
  const int tx = tid & 15;    // output col group
  const int ty = tid >> 4;    // output row group
  const int bm = blockIdx.y * 64;
  const int bn = blockIdx.x * 64;

  float acc[4][4] = {};

  const int am = tid >> 2;            // 0..63 (A tile row)
  const int ak = (tid & 3) << 2;      // 0,4,8,12 (A tile k)
  int arow = bm + am; if (arow >= M) arow = M - 1;   // clamp: safe read
  const float* Aptr = A + (size_t)arow * K + ak;

  const int bk = tid >> 4;            // 0..15 (B tile k)
  const int bn4 = (tid & 15) << 2;    // 0..60 (B tile col)
  const float* Bptr = B + (size_t)bk * Nc + bn + bn4;

  for (int k0 = 0; k0 < K; k0 += 16) {
    float4 av = *(const float4*)(Aptr + k0);
    float4 bv = *(const float4*)(Bptr + (size_t)k0 * Nc);
    __syncthreads();                   // previous iter done reading LDS
    As[ak + 0][am] = av.x;
    As[ak + 1][am] = av.y;
    As[ak + 2][am] = av.z;
    As[ak + 3][am] = av.w;
    *(float4*)&Bs[bk][bn4] = bv;
    __syncthreads();
#pragma unroll
    for (int kk = 0; kk < 16; ++kk) {
      float4 a4 = *(const float4*)&As[kk][ty << 2];
      float4 b4 = *(const float4*)&Bs[kk][tx << 2];
      float aa[4] = {a4.x, a4.y, a4.z, a4.w};
      float bb[4] = {b4.x, b4.y, b4.z, b4.w};
#pragma unroll
      for (int i2 = 0; i2 < 4; ++i2)
#pragma unroll
        for (int j2 = 0; j2 < 4; ++j2) acc[i2][j2] += aa[i2] * bb[j2];
    }
  }

#pragma unroll
  for (int i2 = 0; i2 < 4; ++i2) {
    int row = bm + (ty << 2) + i2;
    if (row < M) {
      float4 o = {acc[i2][0], acc[i2][1], acc[i2][2], acc[i2][3]};
      *(float4*)&C[(size_t)row * Nc + bn + (tx << 2)] = o;
    }
  }
}

// ---------------- layer-1 aggregation, both norms, shared gather ----------------
// one wave per node, lane handles feats {lane, lane+64}; output hg/hp = relu(agg+b1)

__global__ __launch_bounds__(256) void k_agg1(
    const float* __restrict__ hlin, const int* __restrict__ row_ptr,
    const int* __restrict__ csr_src, const float* __restrict__ gn,
    const float* __restrict__ pn, const float* __restrict__ dinv_g,
    const float* __restrict__ dinv_p, const float* __restrict__ b1,
    float* __restrict__ hg, float* __restrict__ hp) {
  int wid = (blockIdx.x * blockDim.x + threadIdx.x) >> 6;
  int lane = threadIdx.x & 63;
  if (wid >= NND) return;
  float sg = dinv_g[wid]; sg *= sg;       // self-loop norm = dinv^2
  float sp = dinv_p[wid]; sp *= sp;
  const float* hr = hlin + (size_t)wid * HID;
  float v0 = hr[lane], v1 = hr[lane + 64];
  float ag0 = v0 * sg, ag1 = v1 * sg;
  float ap0 = v0 * sp, ap1 = v1 * sp;
  int e1 = row_ptr[wid + 1];
  for (int k = row_ptr[wid]; k < e1; ++k) {
    int s = csr_src[k];
    float wg = gn[k], wp = pn[k];
    const float* hs = hlin + (size_t)s * HID;
    float u0 = hs[lane], u1 = hs[lane + 64];
    ag0 += u0 * wg; ag1 += u1 * wg;
    ap0 += u0 * wp; ap1 += u1 * wp;
  }
  float bb0 = b1[lane], bb1 = b1[lane + 64];
  size_t o = (size_t)wid * HID;
  hg[o + lane]      = fmaxf(ag0 + bb0, 0.f);
  hg[o + lane + 64] = fmaxf(ag1 + bb1, 0.f);
  hp[o + lane]      = fmaxf(ap0 + bb0, 0.f);
  hp[o + lane + 64] = fmaxf(ap1 + bb1, 0.f);
}

// ---------------- layer-2 aggregation + attention softmax -> emb ----------------

__global__ __launch_bounds__(256) void k_agg2(
    const float* __restrict__ h2g, const float* __restrict__ h2p,
    const int* __restrict__ row_ptr, const int* __restrict__ csr_src,
    const float* __restrict__ gn, const float* __restrict__ pn,
    const float* __restrict__ dinv_g, const float* __restrict__ dinv_p,
    const float* __restrict__ b2, const float* __restrict__ att_w,
    const float* __restrict__ att_b, float* __restrict__ out_emb) {
  int wid = (blockIdx.x * blockDim.x + threadIdx.x) >> 6;
  int lane = threadIdx.x & 63;
  if (wid >= NND) return;
  float sg = dinv_g[wid]; sg *= sg;
  float sp = dinv_p[wid]; sp *= sp;
  float ga = h2g[(size_t)wid * ENC + lane] * sg;
  float pa = h2p[(size_t)wid * ENC + lane] * sp;
  int e1 = row_ptr[wid + 1];
  for (int k = row_ptr[wid]; k < e1; ++k) {
    int s = csr_src[k];
    float wg = gn[k], wp = pn[k];
    ga += h2g[(size_t)s * ENC + lane] * wg;
    pa += h2p[(size_t)s * ENC + lane] * wp;
  }
  float bb = b2[lane];
  float gv = ga + bb, pv = pa + bb;
  float aw = att_w[lane];
  float lg = gv * aw, lp = pv * aw;
#pragma unroll
  for (int o = 32; o; o >>= 1) {
    lg += __shfl_xor(lg, o, 64);
    lp += __shfl_xor(lp, o, 64);
  }
  float ab = att_b[0];
  lg += ab; lp += ab;
  float mx = fmaxf(lg, lp);
  float eg = expf(lg - mx), ep = expf(lp - mx);
  float w = eg / (eg + ep);
  out_emb[(size_t)wid * ENC + lane] = w * gv + (1.f - w) * pv;
}

// ---------------- class + domain heads (grad-reversal is identity fwd) --------
// 128 nodes/block, emb tile staged in LDS with 65-stride (bank-conflict-free).

__global__ __launch_bounds__(128) void k_head(
    const float* __restrict__ emb,
    const float* __restrict__ cls_w, const float* __restrict__ cls_b,
    const float* __restrict__ dw1, const float* __restrict__ db1,
    const float* __restrict__ dw2, const float* __restrict__ db2,
    float* __restrict__ out_cls, float* __restrict__ out_dom) {
  __shared__ float se[128 * 65];
  const int t = threadIdx.x;
  const int base = blockIdx.x * 128;
  for (int c = 0; c < 64; ++c) {
    int idx = c * 128 + t;                 // 0..8191
    int nl = idx >> 6, k = idx & 63;
    size_t g = (size_t)base * ENC + idx;
    float v = (g < (size_t)NND * ENC) ? emb[g] : 0.f;
    se[nl * 65 + k] = v;
  }
  __syncthreads();

  int node = base + t;
  float c[NCLS], hd[DOM];
#pragma unroll
  for (int j = 0; j < NCLS; ++j) c[j] = cls_b[j];
#pragma unroll
  for (int j = 0; j < DOM; ++j) hd[j] = db1[j];

  for (int k = 0; k < ENC; ++k) {          // rolled; inner dims static
    float ev = se[t * 65 + k];
#pragma unroll
    for (int j = 0; j < NCLS; ++j) c[j] += ev * cls_w[k * NCLS + j];
#pragma unroll
    for (int j = 0; j < DOM; ++j) hd[j] += ev * dw1[k * DOM + j];
  }
  float d0 = db2[0], d1 = db2[1];
#pragma unroll
  for (int j = 0; j < DOM; ++j) {
    float hv = fmaxf(hd[j], 0.f);
    d0 += hv * dw2[j * 2];
    d1 += hv * dw2[j * 2 + 1];
  }
  if (node < NND) {
#pragma unroll
    for (int j = 0; j < NCLS; ++j) out_cls[(size_t)node * NCLS + j] = c[j];
    out_dom[(size_t)node * 2]     = d0;
    out_dom[(size_t)node * 2 + 1] = d1;
  }
}

// ---------------- host ----------------

extern "C" void kernel_launch(void* const* d_in, const int* in_sizes, int n_in,
                              void* d_out, int out_size, void* d_ws, size_t ws_size,
                              hipStream_t stream) {
  const float* x     = (const float*)d_in[0];
  const int*   ei    = (const int*)d_in[1];
  const float* ppmi  = (const float*)d_in[2];
  // d_in[3] = rate: identity in forward, unused
  const float* W1    = (const float*)d_in[4];
  const float* b1    = (const float*)d_in[5];
  const float* W2    = (const float*)d_in[6];
  const float* b2    = (const float*)d_in[7];
  const float* att_w = (const float*)d_in[8];
  const float* att_b = (const float*)d_in[9];
  const float* cls_w = (const float*)d_in[10];
  const float* cls_b = (const float*)d_in[11];
  const float* dw1   = (const float*)d_in[12];
  const float* db1   = (const float*)d_in[13];
  const float* dw2   = (const float*)d_in[14];
  const float* db2   = (const float*)d_in[15];

  const int* src = ei;
  const int* dst = ei + NED;

  // ---- workspace layout ----
  uintptr_t p = (uintptr_t)d_ws;
  auto alloc = [&](size_t bytes) -> void* {
    void* r = (void*)p;
    p += (bytes + 255) & ~(size_t)255;
    return r;
  };
  int*   deg_cnt = (int*)  alloc((size_t)NND * 4);
  int*   cursor  = (int*)  alloc((size_t)NND * 4);
  float* degp    = (float*)alloc((size_t)NND * 4);
  int*   row_ptr = (int*)  alloc((size_t)(NND + 1) * 4);
  int*   psum    = (int*)  alloc((size_t)NBS * 4);
  float* dinv_g  = (float*)alloc((size_t)NND * 4);
  float* dinv_p  = (float*)alloc((size_t)NND * 4);
  int*   csr_src = (int*)  alloc((size_t)NED * 4);
  float* csr_gn  = (float*)alloc((size_t)NED * 4);
  float* csr_pn  = (float*)alloc((size_t)NED * 4);
  float* h_lin   = (float*)alloc((size_t)NND * HID * 4);      // reused as h2 later
  float* hh      = (float*)alloc((size_t)2 * NND * HID * 4);  // [hg ; hp]

  float* hg  = hh;
  float* hp  = hh + (size_t)NND * HID;
  float* h2  = h_lin;                      // reuse: 2*N*64 == N*128
  float* h2g = h2;
  float* h2p = h2 + (size_t)NND * ENC;

  float* out_emb = (float*)d_out;
  float* out_cls = (float*)d_out + (size_t)NND * ENC;
  float* out_dom = (float*)d_out + (size_t)NND * (ENC + NCLS);

  // ---- graph preprocessing ----
  hipMemsetAsync(deg_cnt, 0, (size_t)NND * 4, stream);
  hipMemsetAsync(cursor,  0, (size_t)NND * 4, stream);
  hipMemsetAsync(degp,    0, (size_t)NND * 4, stream);

  k_deg<<<NED / 256, 256, 0, stream>>>(dst, ppmi, deg_cnt, degp);
  k_dinv<<<(NND + 255) / 256, 256, 0, stream>>>(deg_cnt, degp, dinv_g, dinv_p);
  k_scan_a<<<NBS, SCAN_BS, 0, stream>>>(deg_cnt, psum);
  k_scan_b<<<1, 512, 0, stream>>>(psum);
  k_scan_c<<<NBS, SCAN_BS, 0, stream>>>(deg_cnt, psum, row_ptr);
  k_scatter<<<NED / 256, 256, 0, stream>>>(src, dst, ppmi, row_ptr, cursor,
                                           dinv_g, dinv_p, csr_src, csr_gn, csr_pn);

  // ---- encoder ----
  sgemm<<<dim3(HID / 64, (NND + 63) / 64), 256, 0, stream>>>(x, W1, h_lin, NND, FIN, HID);
  k_agg1<<<(NND * 64) / 256, 256, 0, stream>>>(h_lin, row_ptr, csr_src, csr_gn, csr_pn,
                                               dinv_g, dinv_p, b1, hg, hp);
  // fused GEMM over [hg;hp]: M = 2N
  sgemm<<<dim3(ENC / 64, (2 * NND + 63) / 64), 256, 0, stream>>>(hh, W2, h2, 2 * NND, HID, ENC);
  k_agg2<<<(NND * 64) / 256, 256, 0, stream>>>(h2g, h2p, row_ptr, csr_src, csr_gn, csr_pn,
                                               dinv_g, dinv_p, b2, att_w, att_b, out_emb);

  // ---- heads ----
  k_head<<<(NND + 127) / 128, 128, 0, stream>>>(out_emb, cls_w, cls_b, dw1, db1,
                                                dw2, db2, out_cls, out_dom);
}

// Round 2
// 886.402 us; speedup vs baseline: 1.0756x; 1.0756x over previous
//
#include <hip/hip_runtime.h>
#include <math.h>
#include <stdint.h>

#define NND  100000   // nodes
#define NED  1600000  // edges (without self loops)
#define FIN  512
#define HID  128
#define ENC  64
#define NCLS 10
#define DOM  40

#define SCAN_BS 256
#define NBS ((NND + SCAN_BS - 1) / SCAN_BS)   // 391

typedef __attribute__((ext_vector_type(8))) short short8v;
typedef __attribute__((ext_vector_type(4))) float f32x4;
typedef __attribute__((ext_vector_type(4))) unsigned int uint4v;

// ---------------- degree / norm ----------------

__global__ void k_deg(const int* __restrict__ dst, const float* __restrict__ ppmi,
                      int* __restrict__ deg_cnt, float* __restrict__ degp) {
  int e = blockIdx.x * blockDim.x + threadIdx.x;
  if (e >= NED) return;
  int d = dst[e];
  atomicAdd(&deg_cnt[d], 1);
  atomicAdd(&degp[d], ppmi[e]);
}

__global__ void k_dinv(const int* __restrict__ deg_cnt, const float* __restrict__ degp,
                       float* __restrict__ dinv_g, float* __restrict__ dinv_p) {
  int i = blockIdx.x * blockDim.x + threadIdx.x;
  if (i >= NND) return;
  dinv_g[i] = 1.0f / sqrtf((float)deg_cnt[i] + 1.0f);
  dinv_p[i] = 1.0f / sqrtf(degp[i] + 1.0f);
}

// ---------------- 3-kernel exclusive scan (row_ptr) ----------------

__global__ void k_scan_a(const int* __restrict__ deg, int* __restrict__ psum) {
  __shared__ int s[SCAN_BS];
  int t = threadIdx.x, i = blockIdx.x * SCAN_BS + t;
  s[t] = (i < NND) ? deg[i] : 0;
  __syncthreads();
  for (int o = SCAN_BS / 2; o; o >>= 1) {
    if (t < o) s[t] += s[t + o];
    __syncthreads();
  }
  if (t == 0) psum[blockIdx.x] = s[0];
}

__global__ void k_scan_b(int* __restrict__ psum) {
  __shared__ int s[512];
  int t = threadIdx.x;
  int v = (t < NBS) ? psum[t] : 0;
  s[t] = v;
  __syncthreads();
  for (int o = 1; o < 512; o <<= 1) {
    int add = (t >= o) ? s[t - o] : 0;
    __syncthreads();
    s[t] += add;
    __syncthreads();
  }
  if (t < NBS) psum[t] = s[t] - v;   // exclusive
}

__global__ void k_scan_c(const int* __restrict__ deg, const int* __restrict__ psum,
                         int* __restrict__ row_ptr) {
  __shared__ int s[SCAN_BS];
  int t = threadIdx.x, i = blockIdx.x * SCAN_BS + t;
  int v = (i < NND) ? deg[i] : 0;
  s[t] = v;
  __syncthreads();
  for (int o = 1; o < SCAN_BS; o <<= 1) {
    int add = (t >= o) ? s[t - o] : 0;
    __syncthreads();
    s[t] += add;
    __syncthreads();
  }
  if (i < NND) row_ptr[i] = psum[blockIdx.x] + s[t] - v;
  if (i == NND - 1) row_ptr[NND] = psum[blockIdx.x] + s[t];
}

// ---------------- CSR scatter ----------------

__global__ void k_scatter(const int* __restrict__ src, const int* __restrict__ dst,
                          const float* __restrict__ ppmi,
                          const int* __restrict__ row_ptr, int* __restrict__ cursor,
                          const float* __restrict__ dinv_g, const float* __restrict__ dinv_p,
                          int* __restrict__ csr_src, float* __restrict__ csr_gn,
                          float* __restrict__ csr_pn) {
  int e = blockIdx.x * blockDim.x + threadIdx.x;
  if (e >= NED) return;
  int s = src[e], d = dst[e];
  int pos = row_ptr[d] + atomicAdd(&cursor[d], 1);
  csr_src[pos] = s;
  csr_gn[pos] = dinv_g[s] * dinv_g[d];
  csr_pn[pos] = dinv_p[s] * ppmi[e] * dinv_p[d];
}

// ---------------- B preconversion to split-bf16 fragment layout --------------
// B[K][Nc] fp32 -> Bhi/Blo [K/8][Nc][8] bf16 (truncated hi + truncated residual)

template<int NC>
__global__ void k_bprep(const float* __restrict__ B, ushort* __restrict__ bhi,
                        ushort* __restrict__ blo, int K) {
  int id = blockIdx.x * 256 + threadIdx.x;
  if (id >= K * NC) return;
  int k = id / NC, c = id % NC;
  float x = B[id];
  unsigned int u = __float_as_uint(x);
  ushort h = (ushort)(u >> 16);
  float lo = x - __uint_as_float(u & 0xffff0000u);
  ushort l = (ushort)(__float_as_uint(lo) >> 16);
  size_t o = ((size_t)(k >> 3) * NC + c) * 8 + (k & 7);
  bhi[o] = h;
  blo[o] = l;
}

// ---------------- split-bf16 MFMA GEMM ----------------
// C[M,Nc] = A[M,K] @ B[K,Nc]; A fp32 row-major, B preconverted hi/lo.
// Wave tile 64x64 (4x4 16x16x32 frags), block = WR x WC waves, bn = 0 (Nc = WC*64).
// MODE 0: C[r*Nc+c].  MODE 1 (UDAGCN pair): rows [0,NND) -> h2[r][c],
//                     rows [NND,2NND) -> h2[r-NND][64+c]   (node-interleaved g|p)

__device__ inline void split8(const float4 a, const float4 b,
                              short8v& hi, short8v& lo) {
  float f[8] = {a.x, a.y, a.z, a.w, b.x, b.y, b.z, b.w};
  uint4v H, L;
#pragma unroll
  for (int i = 0; i < 4; ++i) {
    unsigned int u0 = __float_as_uint(f[2 * i]);
    unsigned int u1 = __float_as_uint(f[2 * i + 1]);
    H[i] = (u0 >> 16) | (u1 & 0xffff0000u);
    float l0 = f[2 * i]     - __uint_as_float(u0 & 0xffff0000u);
    float l1 = f[2 * i + 1] - __uint_as_float(u1 & 0xffff0000u);
    L[i] = (__float_as_uint(l0) >> 16) | (__float_as_uint(l1) & 0xffff0000u);
  }
  hi = __builtin_bit_cast(short8v, H);
  lo = __builtin_bit_cast(short8v, L);
}

template<int WR, int WC, int MODE>
__global__ __launch_bounds__(256, 2) void gemm_split(
    const float* __restrict__ A, const ushort* __restrict__ Bhi,
    const ushort* __restrict__ Blo, float* __restrict__ C,
    int M, int K, int Nc) {
  const int lane = threadIdx.x & 63;
  const int w = threadIdx.x >> 6;
  const int wr = w / WC, wc = w % WC;
  const int g = lane >> 4;          // k-slot group
  const int l16 = lane & 15;
  const int row_base = blockIdx.x * (WR * 64) + wr * 64;

  size_t arow[4];
#pragma unroll
  for (int m = 0; m < 4; ++m) {
    int r = row_base + m * 16 + l16;
    if (r >= M) r = M - 1;          // clamp: safe read, rows discarded at store
    arow[m] = (size_t)r * K;
  }
  int coln[4];
#pragma unroll
  for (int n = 0; n < 4; ++n) coln[n] = wc * 64 + n * 16 + l16;

  f32x4 acc[4][4] = {};

  for (int k0 = 0; k0 < K; k0 += 32) {
    float4 a0[4], a1[4];
#pragma unroll
    for (int m = 0; m < 4; ++m) {
      const float* p = A + arow[m] + k0 + g * 8;
      a0[m] = *(const float4*)p;
      a1[m] = *(const float4*)(p + 4);
    }
    short8v bh[4], bl[4];
    const int kc = (k0 >> 3) + g;
#pragma unroll
    for (int n = 0; n < 4; ++n) {
      size_t off = ((size_t)kc * Nc + coln[n]) * 8;
      bh[n] = *(const short8v*)(Bhi + off);
      bl[n] = *(const short8v*)(Blo + off);
    }
    short8v ah[4], al[4];
#pragma unroll
    for (int m = 0; m < 4; ++m) split8(a0[m], a1[m], ah[m], al[m]);
#pragma unroll
    for (int m = 0; m < 4; ++m)
#pragma unroll
      for (int n = 0; n < 4; ++n) {
        acc[m][n] = __builtin_amdgcn_mfma_f32_16x16x32_bf16(ah[m], bh[n], acc[m][n], 0, 0, 0);
        acc[m][n] = __builtin_amdgcn_mfma_f32_16x16x32_bf16(al[m], bh[n], acc[m][n], 0, 0, 0);
        acc[m][n] = __builtin_amdgcn_mfma_f32_16x16x32_bf16(ah[m], bl[n], acc[m][n], 0, 0, 0);
      }
  }

  // C/D layout: col = lane&15, row = (lane>>4)*4 + reg
#pragma unroll
  for (int m = 0; m < 4; ++m)
#pragma unroll
    for (int i = 0; i < 4; ++i) {
      int r = row_base + m * 16 + g * 4 + i;
      if (r < M) {
#pragma unroll
        for (int n = 0; n < 4; ++n) {
          int c = coln[n];
          size_t o;
          if (MODE == 0) o = (size_t)r * Nc + c;
          else o = (r < NND) ? ((size_t)r * 128 + c)
                             : ((size_t)(r - NND) * 128 + 64 + c);
          C[o] = acc[m][n][i];
        }
      }
    }
}

// ---------------- layer-1 aggregation, both norms, shared gather --------------
// one wave per node; lane handles feats {2*lane, 2*lane+1} as float2

__global__ __launch_bounds__(256) void k_agg1(
    const float* __restrict__ hlin, const int* __restrict__ row_ptr,
    const int* __restrict__ csr_src, const float* __restrict__ gn,
    const float* __restrict__ pn, const float* __restrict__ dinv_g,
    const float* __restrict__ dinv_p, const float* __restrict__ b1,
    float* __restrict__ hg, float* __restrict__ hp) {
  int wid = (blockIdx.x * blockDim.x + threadIdx.x) >> 6;
  int lane = threadIdx.x & 63;
  if (wid >= NND) return;
  float sg = dinv_g[wid]; sg *= sg;       // self-loop norm = dinv^2
  float sp = dinv_p[wid]; sp *= sp;
  float2 v = *(const float2*)(hlin + (size_t)wid * HID + 2 * lane);
  float ag0 = v.x * sg, ag1 = v.y * sg;
  float ap0 = v.x * sp, ap1 = v.y * sp;
  int e1 = row_ptr[wid + 1];
  for (int k = row_ptr[wid]; k < e1; ++k) {
    int s = csr_src[k];
    float wg = gn[k], wp = pn[k];
    float2 u = *(const float2*)(hlin + (size_t)s * HID + 2 * lane);
    ag0 += u.x * wg; ag1 += u.y * wg;
    ap0 += u.x * wp; ap1 += u.y * wp;
  }
  float2 bb = *(const float2*)(b1 + 2 * lane);
  size_t o = (size_t)wid * HID + 2 * lane;
  float2 og = {fmaxf(ag0 + bb.x, 0.f), fmaxf(ag1 + bb.y, 0.f)};
  float2 op = {fmaxf(ap0 + bb.x, 0.f), fmaxf(ap1 + bb.y, 0.f)};
  *(float2*)(hg + o) = og;
  *(float2*)(hp + o) = op;
}

// ---------------- layer-2 aggregation + attention softmax -> emb --------------
// h2 node-interleaved: h2[node][0:64] = g, h2[node][64:128] = p

__global__ __launch_bounds__(256) void k_agg2(
    const float* __restrict__ h2,
    const int* __restrict__ row_ptr, const int* __restrict__ csr_src,
    const float* __restrict__ gn, const float* __restrict__ pn,
    const float* __restrict__ dinv_g, const float* __restrict__ dinv_p,
    const float* __restrict__ b2, const float* __restrict__ att_w,
    const float* __restrict__ att_b, float* __restrict__ out_emb) {
  int wid = (blockIdx.x * blockDim.x + threadIdx.x) >> 6;
  int lane = threadIdx.x & 63;
  if (wid >= NND) return;
  float sg = dinv_g[wid]; sg *= sg;
  float sp = dinv_p[wid]; sp *= sp;
  const float* hr = h2 + (size_t)wid * 128;
  float ga = hr[lane] * sg;
  float pa = hr[64 + lane] * sp;
  int e1 = row_ptr[wid + 1];
  for (int k = row_ptr[wid]; k < e1; ++k) {
    int s = csr_src[k];
    float wg = gn[k], wp = pn[k];
    const float* hs = h2 + (size_t)s * 128;
    ga += hs[lane] * wg;
    pa += hs[64 + lane] * wp;
  }
  float bb = b2[lane];
  float gv = ga + bb, pv = pa + bb;
  float aw = att_w[lane];
  float lg = gv * aw, lp = pv * aw;
#pragma unroll
  for (int o = 32; o; o >>= 1) {
    lg += __shfl_xor(lg, o, 64);
    lp += __shfl_xor(lp, o, 64);
  }
  float ab = att_b[0];
  lg += ab; lp += ab;
  float mx = fmaxf(lg, lp);
  float eg = expf(lg - mx), ep = expf(lp - mx);
  float w = eg / (eg + ep);
  out_emb[(size_t)wid * ENC + lane] = w * gv + (1.f - w) * pv;
}

// ---------------- class + domain heads --------------

__global__ __launch_bounds__(128) void k_head(
    const float* __restrict__ emb,
    const float* __restrict__ cls_w, const float* __restrict__ cls_b,
    const float* __restrict__ dw1, const float* __restrict__ db1,
    const float* __restrict__ dw2, const float* __restrict__ db2,
    float* __restrict__ out_cls, float* __restrict__ out_dom) {
  __shared__ float se[128 * 65];
  const int t = threadIdx.x;
  const int base = blockIdx.x * 128;
  for (int c = 0; c < 64; ++c) {
    int idx = c * 128 + t;
    int nl = idx >> 6, k = idx & 63;
    size_t g = (size_t)base * ENC + idx;
    float v = (g < (size_t)NND * ENC) ? emb[g] : 0.f;
    se[nl * 65 + k] = v;
  }
  __syncthreads();

  int node = base + t;
  float c[NCLS], hd[DOM];
#pragma unroll
  for (int j = 0; j < NCLS; ++j) c[j] = cls_b[j];
#pragma unroll
  for (int j = 0; j < DOM; ++j) hd[j] = db1[j];

  for (int k = 0; k < ENC; ++k) {
    float ev = se[t * 65 + k];
#pragma unroll
    for (int j = 0; j < NCLS; ++j) c[j] += ev * cls_w[k * NCLS + j];
#pragma unroll
    for (int j = 0; j < DOM; ++j) hd[j] += ev * dw1[k * DOM + j];
  }
  float d0 = db2[0], d1 = db2[1];
#pragma unroll
  for (int j = 0; j < DOM; ++j) {
    float hv = fmaxf(hd[j], 0.f);
    d0 += hv * dw2[j * 2];
    d1 += hv * dw2[j * 2 + 1];
  }
  if (node < NND) {
#pragma unroll
    for (int j = 0; j < NCLS; ++j) out_cls[(size_t)node * NCLS + j] = c[j];
    out_dom[(size_t)node * 2]     = d0;
    out_dom[(size_t)node * 2 + 1] = d1;
  }
}

// ---------------- host ----------------

extern "C" void kernel_launch(void* const* d_in, const int* in_sizes, int n_in,
                              void* d_out, int out_size, void* d_ws, size_t ws_size,
                              hipStream_t stream) {
  const float* x     = (const float*)d_in[0];
  const int*   ei    = (const int*)d_in[1];
  const float* ppmi  = (const float*)d_in[2];
  const float* W1    = (const float*)d_in[4];
  const float* b1    = (const float*)d_in[5];
  const float* W2    = (const float*)d_in[6];
  const float* b2    = (const float*)d_in[7];
  const float* att_w = (const float*)d_in[8];
  const float* att_b = (const float*)d_in[9];
  const float* cls_w = (const float*)d_in[10];
  const float* cls_b = (const float*)d_in[11];
  const float* dw1   = (const float*)d_in[12];
  const float* db1   = (const float*)d_in[13];
  const float* dw2   = (const float*)d_in[14];
  const float* db2   = (const float*)d_in[15];

  const int* src = ei;
  const int* dst = ei + NED;

  uintptr_t p = (uintptr_t)d_ws;
  auto alloc = [&](size_t bytes) -> void* {
    void* r = (void*)p;
    p += (bytes + 255) & ~(size_t)255;
    return r;
  };
  int*    deg_cnt = (int*)   alloc((size_t)NND * 4);
  int*    cursor  = (int*)   alloc((size_t)NND * 4);
  float*  degp    = (float*) alloc((size_t)NND * 4);
  int*    row_ptr = (int*)   alloc((size_t)(NND + 1) * 4);
  int*    psum    = (int*)   alloc((size_t)NBS * 4);
  float*  dinv_g  = (float*) alloc((size_t)NND * 4);
  float*  dinv_p  = (float*) alloc((size_t)NND * 4);
  int*    csr_src = (int*)   alloc((size_t)NED * 4);
  float*  csr_gn  = (float*) alloc((size_t)NED * 4);
  float*  csr_pn  = (float*) alloc((size_t)NED * 4);
  ushort* b1hi    = (ushort*)alloc((size_t)FIN * HID * 2);
  ushort* b1lo    = (ushort*)alloc((size_t)FIN * HID * 2);
  ushort* b2hi    = (ushort*)alloc((size_t)HID * ENC * 2);
  ushort* b2lo    = (ushort*)alloc((size_t)HID * ENC * 2);
  float*  h_lin   = (float*) alloc((size_t)NND * HID * 4);      // reused as h2
  float*  hh      = (float*) alloc((size_t)2 * NND * HID * 4);  // [hg ; hp]

  float* hg = hh;
  float* hp = hh + (size_t)NND * HID;
  float* h2 = h_lin;   // node-interleaved [N][128]: g | p  (2*N*64 == N*128)

  float* out_emb = (float*)d_out;
  float* out_cls = (float*)d_out + (size_t)NND * ENC;
  float* out_dom = (float*)d_out + (size_t)NND * (ENC + NCLS);

  // ---- graph preprocessing ----
  hipMemsetAsync(deg_cnt, 0, (size_t)NND * 4, stream);
  hipMemsetAsync(cursor,  0, (size_t)NND * 4, stream);
  hipMemsetAsync(degp,    0, (size_t)NND * 4, stream);

  k_deg<<<NED / 256, 256, 0, stream>>>(dst, ppmi, deg_cnt, degp);
  k_dinv<<<(NND + 255) / 256, 256, 0, stream>>>(deg_cnt, degp, dinv_g, dinv_p);
  k_scan_a<<<NBS, SCAN_BS, 0, stream>>>(deg_cnt, psum);
  k_scan_b<<<1, 512, 0, stream>>>(psum);
  k_scan_c<<<NBS, SCAN_BS, 0, stream>>>(deg_cnt, psum, row_ptr);
  k_scatter<<<NED / 256, 256, 0, stream>>>(src, dst, ppmi, row_ptr, cursor,
                                           dinv_g, dinv_p, csr_src, csr_gn, csr_pn);

  // ---- weight preconversion (tiny) ----
  k_bprep<HID><<<(FIN * HID + 255) / 256, 256, 0, stream>>>(W1, b1hi, b1lo, FIN);
  k_bprep<ENC><<<(HID * ENC + 255) / 256, 256, 0, stream>>>(W2, b2hi, b2lo, HID);

  // ---- encoder ----
  // h_lin = x @ W1   (M=100000, K=512, Nc=128), 2x2 waves
  gemm_split<2, 2, 0><<<(NND + 127) / 128, 256, 0, stream>>>(
      x, b1hi, b1lo, h_lin, NND, FIN, HID);
  k_agg1<<<(NND * 64) / 256, 256, 0, stream>>>(h_lin, row_ptr, csr_src, csr_gn, csr_pn,
                                               dinv_g, dinv_p, b1, hg, hp);
  // h2 = [hg;hp] @ W2 (M=2N, K=128, Nc=64), 4x1 waves, node-interleaved output
  gemm_split<4, 1, 1><<<(2 * NND + 255) / 256, 256, 0, stream>>>(
      hh, b2hi, b2lo, h2, 2 * NND, HID, ENC);
  k_agg2<<<(NND * 64) / 256, 256, 0, stream>>>(h2, row_ptr, csr_src, csr_gn, csr_pn,
                                               dinv_g, dinv_p, b2, att_w, att_b, out_emb);

  // ---- heads ----
  k_head<<<(NND + 127) / 128, 128, 0, stream>>>(out_emb, cls_w, cls_b, dw1, db1,
                                                dw2, db2, out_cls, out_dom);
}

// Round 3
// 754.554 us; speedup vs baseline: 1.2635x; 1.1747x over previous
//
#include <hip/hip_runtime.h>
#include <math.h>
#include <stdint.h>

#define NND  100000   // nodes
#define NED  1600000  // edges (without self loops)
#define FIN  512
#define HID  128
#define ENC  64
#define NCLS 10
#define DOM  40

#define SCAN_BS 256
#define NBS ((NND + SCAN_BS - 1) / SCAN_BS)   // 391

typedef __attribute__((ext_vector_type(8))) short short8v;
typedef __attribute__((ext_vector_type(4))) float f32x4;
typedef __attribute__((ext_vector_type(4))) unsigned int uint4v;

// ---------------- degree / norm ----------------

__global__ void k_deg(const int* __restrict__ dst, const float* __restrict__ ppmi,
                      int* __restrict__ deg_cnt, float* __restrict__ degp) {
  int e = blockIdx.x * blockDim.x + threadIdx.x;
  if (e >= NED) return;
  int d = dst[e];
  atomicAdd(&deg_cnt[d], 1);
  atomicAdd(&degp[d], ppmi[e]);
}

__global__ void k_dinv(const int* __restrict__ deg_cnt, const float* __restrict__ degp,
                       float* __restrict__ dinv_g, float* __restrict__ dinv_p) {
  int i = blockIdx.x * blockDim.x + threadIdx.x;
  if (i >= NND) return;
  dinv_g[i] = 1.0f / sqrtf((float)deg_cnt[i] + 1.0f);
  dinv_p[i] = 1.0f / sqrtf(degp[i] + 1.0f);
}

// ---------------- 3-kernel exclusive scan (row_ptr) ----------------

__global__ void k_scan_a(const int* __restrict__ deg, int* __restrict__ psum) {
  __shared__ int s[SCAN_BS];
  int t = threadIdx.x, i = blockIdx.x * SCAN_BS + t;
  s[t] = (i < NND) ? deg[i] : 0;
  __syncthreads();
  for (int o = SCAN_BS / 2; o; o >>= 1) {
    if (t < o) s[t] += s[t + o];
    __syncthreads();
  }
  if (t == 0) psum[blockIdx.x] = s[0];
}

__global__ void k_scan_b(int* __restrict__ psum) {
  __shared__ int s[512];
  int t = threadIdx.x;
  int v = (t < NBS) ? psum[t] : 0;
  s[t] = v;
  __syncthreads();
  for (int o = 1; o < 512; o <<= 1) {
    int add = (t >= o) ? s[t - o] : 0;
    __syncthreads();
    s[t] += add;
    __syncthreads();
  }
  if (t < NBS) psum[t] = s[t] - v;   // exclusive
}

__global__ void k_scan_c(const int* __restrict__ deg, const int* __restrict__ psum,
                         int* __restrict__ row_ptr) {
  __shared__ int s[SCAN_BS];
  int t = threadIdx.x, i = blockIdx.x * SCAN_BS + t;
  int v = (i < NND) ? deg[i] : 0;
  s[t] = v;
  __syncthreads();
  for (int o = 1; o < SCAN_BS; o <<= 1) {
    int add = (t >= o) ? s[t - o] : 0;
    __syncthreads();
    s[t] += add;
    __syncthreads();
  }
  if (i < NND) row_ptr[i] = psum[blockIdx.x] + s[t] - v;
  if (i == NND - 1) row_ptr[NND] = psum[blockIdx.x] + s[t];
}

// ---------------- CSR scatter: packed 16B record {src, gn, pn, 0} -------------

__global__ void k_scatter(const int* __restrict__ src, const int* __restrict__ dst,
                          const float* __restrict__ ppmi,
                          const int* __restrict__ row_ptr, int* __restrict__ cursor,
                          const float* __restrict__ dinv_g, const float* __restrict__ dinv_p,
                          int4* __restrict__ csr) {
  int e = blockIdx.x * blockDim.x + threadIdx.x;
  if (e >= NED) return;
  int s = src[e], d = dst[e];
  int pos = row_ptr[d] + atomicAdd(&cursor[d], 1);
  int4 rec;
  rec.x = s;
  rec.y = __float_as_int(dinv_g[s] * dinv_g[d]);
  rec.z = __float_as_int(dinv_p[s] * ppmi[e] * dinv_p[d]);
  rec.w = 0;
  csr[pos] = rec;
}

// ---------------- B preconversion to split-bf16 fragment layout --------------
// B[K][Nc] fp32 -> Bhi/Blo [K/8][Nc][8] bf16 (truncated hi + truncated residual)

template<int NC>
__global__ void k_bprep(const float* __restrict__ B, ushort* __restrict__ bhi,
                        ushort* __restrict__ blo, int K) {
  int id = blockIdx.x * 256 + threadIdx.x;
  if (id >= K * NC) return;
  int k = id / NC, c = id % NC;
  float x = B[id];
  unsigned int u = __float_as_uint(x);
  ushort h = (ushort)(u >> 16);
  float lo = x - __uint_as_float(u & 0xffff0000u);
  ushort l = (ushort)(__float_as_uint(lo) >> 16);
  size_t o = ((size_t)(k >> 3) * NC + c) * 8 + (k & 7);
  bhi[o] = h;
  blo[o] = l;
}

// ---------------- split-bf16 MFMA GEMM ----------------
// C[M,Nc] = A[M,K] @ B[K,Nc]; B preconverted hi/lo fragment layout.
// ASPLIT=0: A fp32 row-major (split in-register).
// ASPLIT=1: A rows are [hi bf16 x K | lo bf16 x K] (2K ushorts per row).
// Wave tile 64x64 (4x4 16x16x32 frags), block = WR x WC waves.
// MODE 0: C[r*Nc+c].  MODE 1: rows [0,NND) -> h2[r][c], rows [NND,2NND) ->
//         h2[r-NND][64+c]  (node-interleaved g|p).

__device__ inline void split8(const float4 a, const float4 b,
                              short8v& hi, short8v& lo) {
  float f[8] = {a.x, a.y, a.z, a.w, b.x, b.y, b.z, b.w};
  uint4v H, L;
#pragma unroll
  for (int i = 0; i < 4; ++i) {
    unsigned int u0 = __float_as_uint(f[2 * i]);
    unsigned int u1 = __float_as_uint(f[2 * i + 1]);
    H[i] = (u0 >> 16) | (u1 & 0xffff0000u);
    float l0 = f[2 * i]     - __uint_as_float(u0 & 0xffff0000u);
    float l1 = f[2 * i + 1] - __uint_as_float(u1 & 0xffff0000u);
    L[i] = (__float_as_uint(l0) >> 16) | (__float_as_uint(l1) & 0xffff0000u);
  }
  hi = __builtin_bit_cast(short8v, H);
  lo = __builtin_bit_cast(short8v, L);
}

template<int WR, int WC, int MODE, int ASPLIT>
__global__ __launch_bounds__(256, 2) void gemm_split(
    const void* __restrict__ Av, const ushort* __restrict__ Bhi,
    const ushort* __restrict__ Blo, float* __restrict__ C,
    int M, int K, int Nc) {
  const int lane = threadIdx.x & 63;
  const int w = threadIdx.x >> 6;
  const int wr = w / WC, wc = w % WC;
  const int g = lane >> 4;          // k-slot group
  const int l16 = lane & 15;
  const int row_base = blockIdx.x * (WR * 64) + wr * 64;

  size_t arow[4];
#pragma unroll
  for (int m = 0; m < 4; ++m) {
    int r = row_base + m * 16 + l16;
    if (r >= M) r = M - 1;          // clamp: safe read, rows discarded at store
    arow[m] = (size_t)r * (ASPLIT ? 2 * K : K);
  }
  int coln[4];
#pragma unroll
  for (int n = 0; n < 4; ++n) coln[n] = wc * 64 + n * 16 + l16;

  f32x4 acc[4][4] = {};

  for (int k0 = 0; k0 < K; k0 += 32) {
    short8v ah[4], al[4];
    if constexpr (ASPLIT) {
      const ushort* As = (const ushort*)Av;
#pragma unroll
      for (int m = 0; m < 4; ++m) {
        const ushort* p = As + arow[m] + k0 + g * 8;
        ah[m] = *(const short8v*)p;
        al[m] = *(const short8v*)(p + K);
      }
    } else {
      const float* A = (const float*)Av;
      float4 a0[4], a1[4];
#pragma unroll
      for (int m = 0; m < 4; ++m) {
        const float* p = A + arow[m] + k0 + g * 8;
        a0[m] = *(const float4*)p;
        a1[m] = *(const float4*)(p + 4);
      }
#pragma unroll
      for (int m = 0; m < 4; ++m) split8(a0[m], a1[m], ah[m], al[m]);
    }
    short8v bh[4], bl[4];
    const int kc = (k0 >> 3) + g;
#pragma unroll
    for (int n = 0; n < 4; ++n) {
      size_t off = ((size_t)kc * Nc + coln[n]) * 8;
      bh[n] = *(const short8v*)(Bhi + off);
      bl[n] = *(const short8v*)(Blo + off);
    }
#pragma unroll
    for (int m = 0; m < 4; ++m)
#pragma unroll
      for (int n = 0; n < 4; ++n) {
        acc[m][n] = __builtin_amdgcn_mfma_f32_16x16x32_bf16(ah[m], bh[n], acc[m][n], 0, 0, 0);
        acc[m][n] = __builtin_amdgcn_mfma_f32_16x16x32_bf16(al[m], bh[n], acc[m][n], 0, 0, 0);
        acc[m][n] = __builtin_amdgcn_mfma_f32_16x16x32_bf16(ah[m], bl[n], acc[m][n], 0, 0, 0);
      }
  }

  // C/D layout: col = lane&15, row = (lane>>4)*4 + reg
#pragma unroll
  for (int m = 0; m < 4; ++m)
#pragma unroll
    for (int i = 0; i < 4; ++i) {
      int r = row_base + m * 16 + g * 4 + i;
      if (r < M) {
#pragma unroll
        for (int n = 0; n < 4; ++n) {
          int c = coln[n];
          size_t o;
          if (MODE == 0) o = (size_t)r * Nc + c;
          else o = (r < NND) ? ((size_t)r * 128 + c)
                             : ((size_t)(r - NND) * 128 + 64 + c);
          C[o] = acc[m][n][i];
        }
      }
    }
}

// ---------------- split one fp32 -> hi/lo truncated bf16 ----------------

__device__ inline void split1(float x, ushort& h, ushort& l) {
  unsigned int u = __float_as_uint(x);
  h = (ushort)(u >> 16);
  float r = x - __uint_as_float(u & 0xffff0000u);
  l = (ushort)(__float_as_uint(r) >> 16);
}

// ---------------- layer-1 aggregation, both norms ----------------
// one wave per node; lanes 0-31 even edges, 32-63 odd edges; float4/lane.
// outputs relu(agg+b1) as split-bf16 rows [hi128|lo128] (hg row wid, hp row NND+wid)

__global__ __launch_bounds__(256) void k_agg1(
    const float* __restrict__ hlin, const int* __restrict__ row_ptr,
    const int4* __restrict__ csr,
    const float* __restrict__ dinv_g, const float* __restrict__ dinv_p,
    const float* __restrict__ b1, ushort* __restrict__ hhs) {
  int wid = (blockIdx.x * blockDim.x + threadIdx.x) >> 6;
  int lane = threadIdx.x & 63;
  if (wid >= NND) return;
  const int half = lane >> 5;
  const int l5 = lane & 31;
  float sg = dinv_g[wid]; sg *= sg;       // self-loop norm = dinv^2
  float sp = dinv_p[wid]; sp *= sp;

  float agx = 0.f, agy = 0.f, agz = 0.f, agw = 0.f;
  float apx = 0.f, apy = 0.f, apz = 0.f, apw = 0.f;
  if (half == 0) {
    float4 v = *(const float4*)(hlin + (size_t)wid * HID + 4 * l5);
    agx = v.x * sg; agy = v.y * sg; agz = v.z * sg; agw = v.w * sg;
    apx = v.x * sp; apy = v.y * sp; apz = v.z * sp; apw = v.w * sp;
  }

  int e0 = row_ptr[wid], e1 = row_ptr[wid + 1];
  int k = e0 + half;
  if (k < e1) {
    int4 rec = csr[k];
    while (true) {
      int kn = k + 2;
      int4 nrec = csr[kn < e1 ? kn : k];        // clamped prefetch
      float wg = __int_as_float(rec.y);
      float wp = __int_as_float(rec.z);
      float4 u = *(const float4*)(hlin + (size_t)rec.x * HID + 4 * l5);
      agx = fmaf(u.x, wg, agx); agy = fmaf(u.y, wg, agy);
      agz = fmaf(u.z, wg, agz); agw = fmaf(u.w, wg, agw);
      apx = fmaf(u.x, wp, apx); apy = fmaf(u.y, wp, apy);
      apz = fmaf(u.z, wp, apz); apw = fmaf(u.w, wp, apw);
      if (kn >= e1) break;
      k = kn; rec = nrec;
    }
  }

  // combine even/odd halves
  agx += __shfl_xor(agx, 32); agy += __shfl_xor(agy, 32);
  agz += __shfl_xor(agz, 32); agw += __shfl_xor(agw, 32);
  apx += __shfl_xor(apx, 32); apy += __shfl_xor(apy, 32);
  apz += __shfl_xor(apz, 32); apw += __shfl_xor(apw, 32);

  float4 bb = *(const float4*)(b1 + 4 * l5);
  float r0, r1, r2, r3;
  if (half == 0) { r0 = agx + bb.x; r1 = agy + bb.y; r2 = agz + bb.z; r3 = agw + bb.w; }
  else           { r0 = apx + bb.x; r1 = apy + bb.y; r2 = apz + bb.z; r3 = apw + bb.w; }
  r0 = fmaxf(r0, 0.f); r1 = fmaxf(r1, 0.f); r2 = fmaxf(r2, 0.f); r3 = fmaxf(r3, 0.f);

  ushort4 hv, lv;
  split1(r0, hv.x, lv.x); split1(r1, hv.y, lv.y);
  split1(r2, hv.z, lv.z); split1(r3, hv.w, lv.w);
  size_t rowbase = (size_t)(half ? NND + wid : wid) * (2 * HID);
  *(ushort4*)(hhs + rowbase + 4 * l5) = hv;           // hi block [0,128)
  *(ushort4*)(hhs + rowbase + HID + 4 * l5) = lv;     // lo block [128,256)
}

// ---------------- layer-2 aggregation + attention softmax -> emb --------------
// h2 node-interleaved: h2[node][0:64]=g, [64:128]=p.  One wave per node.
// lane = (edge parity ep)<<5 | (branch q)<<4 | t;  float4 covers feats 4t..4t+3.

__global__ __launch_bounds__(256) void k_agg2(
    const float* __restrict__ h2, const int* __restrict__ row_ptr,
    const int4* __restrict__ csr,
    const float* __restrict__ dinv_g, const float* __restrict__ dinv_p,
    const float* __restrict__ b2, const float* __restrict__ att_w,
    const float* __restrict__ att_b, float* __restrict__ out_emb) {
  int wid = (blockIdx.x * blockDim.x + threadIdx.x) >> 6;
  int lane = threadIdx.x & 63;
  if (wid >= NND) return;
  const int ep = lane >> 5;
  const int q  = (lane >> 4) & 1;
  const int t  = lane & 15;
  float sg = dinv_g[wid]; sg *= sg;
  float sp = dinv_p[wid]; sp *= sp;
  const float sw = q ? sp : sg;

  float ax = 0.f, ay = 0.f, az = 0.f, azw = 0.f;
  if (ep == 0) {
    float4 v = *(const float4*)(h2 + (size_t)wid * 128 + q * 64 + 4 * t);
    ax = v.x * sw; ay = v.y * sw; az = v.z * sw; azw = v.w * sw;
  }

  int e0 = row_ptr[wid], e1 = row_ptr[wid + 1];
  int k = e0 + ep;
  if (k < e1) {
    int4 rec = csr[k];
    while (true) {
      int kn = k + 2;
      int4 nrec = csr[kn < e1 ? kn : k];
      float w = __int_as_float(q ? rec.z : rec.y);
      float4 u = *(const float4*)(h2 + (size_t)rec.x * 128 + q * 64 + 4 * t);
      ax = fmaf(u.x, w, ax); ay = fmaf(u.y, w, ay);
      az = fmaf(u.z, w, az); azw = fmaf(u.w, w, azw);
      if (kn >= e1) break;
      k = kn; rec = nrec;
    }
  }

  // combine edge-parity halves: lanes 0-15 g totals, 16-31 p totals
  ax += __shfl_xor(ax, 32); ay += __shfl_xor(ay, 32);
  az += __shfl_xor(az, 32); azw += __shfl_xor(azw, 32);

  float4 bb = *(const float4*)(b2 + 4 * t);
  float vx = ax + bb.x, vy = ay + bb.y, vz = az + bb.z, vw = azw + bb.w;

  float4 aw4 = *(const float4*)(att_w + 4 * t);
  float part = vx * aw4.x + vy * aw4.y + vz * aw4.z + vw * aw4.w;
  part += __shfl_xor(part, 8);
  part += __shfl_xor(part, 4);
  part += __shfl_xor(part, 2);
  part += __shfl_xor(part, 1);
  float other = __shfl_xor(part, 16);
  float ab = att_b[0];
  float lg = (q ? other : part) + ab;
  float lp = (q ? part : other) + ab;
  float mx = fmaxf(lg, lp);
  float egv = expf(lg - mx), epv = expf(lp - mx);
  float wsm = egv / (egv + epv);        // weight of g branch

  float ox = __shfl_xor(vx, 16);
  float oy = __shfl_xor(vy, 16);
  float oz = __shfl_xor(vz, 16);
  float ow = __shfl_xor(vw, 16);
  if (lane < 16) {                       // val = gv, other = pv
    float4 o;
    o.x = wsm * vx + (1.f - wsm) * ox;
    o.y = wsm * vy + (1.f - wsm) * oy;
    o.z = wsm * vz + (1.f - wsm) * oz;
    o.w = wsm * vw + (1.f - wsm) * ow;
    *(float4*)(out_emb + (size_t)wid * 64 + 4 * t) = o;
  }
}

// ---------------- class + domain heads --------------

__global__ __launch_bounds__(128) void k_head(
    const float* __restrict__ emb,
    const float* __restrict__ cls_w, const float* __restrict__ cls_b,
    const float* __restrict__ dw1, const float* __restrict__ db1,
    const float* __restrict__ dw2, const float* __restrict__ db2,
    float* __restrict__ out_cls, float* __restrict__ out_dom) {
  __shared__ float se[128 * 65];
  const int t = threadIdx.x;
  const int base = blockIdx.x * 128;
  for (int c = 0; c < 64; ++c) {
    int idx = c * 128 + t;
    int nl = idx >> 6, k = idx & 63;
    size_t g = (size_t)base * ENC + idx;
    float v = (g < (size_t)NND * ENC) ? emb[g] : 0.f;
    se[nl * 65 + k] = v;
  }
  __syncthreads();

  int node = base + t;
  float c[NCLS], hd[DOM];
#pragma unroll
  for (int j = 0; j < NCLS; ++j) c[j] = cls_b[j];
#pragma unroll
  for (int j = 0; j < DOM; ++j) hd[j] = db1[j];

  for (int k = 0; k < ENC; ++k) {
    float ev = se[t * 65 + k];
#pragma unroll
    for (int j = 0; j < NCLS; ++j) c[j] += ev * cls_w[k * NCLS + j];
#pragma unroll
    for (int j = 0; j < DOM; ++j) hd[j] += ev * dw1[k * DOM + j];
  }
  float d0 = db2[0], d1 = db2[1];
#pragma unroll
  for (int j = 0; j < DOM; ++j) {
    float hv = fmaxf(hd[j], 0.f);
    d0 += hv * dw2[j * 2];
    d1 += hv * dw2[j * 2 + 1];
  }
  if (node < NND) {
#pragma unroll
    for (int j = 0; j < NCLS; ++j) out_cls[(size_t)node * NCLS + j] = c[j];
    out_dom[(size_t)node * 2]     = d0;
    out_dom[(size_t)node * 2 + 1] = d1;
  }
}

// ---------------- host ----------------

extern "C" void kernel_launch(void* const* d_in, const int* in_sizes, int n_in,
                              void* d_out, int out_size, void* d_ws, size_t ws_size,
                              hipStream_t stream) {
  const float* x     = (const float*)d_in[0];
  const int*   ei    = (const int*)d_in[1];
  const float* ppmi  = (const float*)d_in[2];
  const float* W1    = (const float*)d_in[4];
  const float* b1    = (const float*)d_in[5];
  const float* W2    = (const float*)d_in[6];
  const float* b2    = (const float*)d_in[7];
  const float* att_w = (const float*)d_in[8];
  const float* att_b = (const float*)d_in[9];
  const float* cls_w = (const float*)d_in[10];
  const float* cls_b = (const float*)d_in[11];
  const float* dw1   = (const float*)d_in[12];
  const float* db1   = (const float*)d_in[13];
  const float* dw2   = (const float*)d_in[14];
  const float* db2   = (const float*)d_in[15];

  const int* src = ei;
  const int* dst = ei + NED;

  uintptr_t p = (uintptr_t)d_ws;
  auto alloc = [&](size_t bytes) -> void* {
    void* r = (void*)p;
    p += (bytes + 255) & ~(size_t)255;
    return r;
  };
  int*    deg_cnt = (int*)   alloc((size_t)NND * 4);
  int*    cursor  = (int*)   alloc((size_t)NND * 4);
  float*  degp    = (float*) alloc((size_t)NND * 4);
  int*    row_ptr = (int*)   alloc((size_t)(NND + 1) * 4);
  int*    psum    = (int*)   alloc((size_t)NBS * 4);
  float*  dinv_g  = (float*) alloc((size_t)NND * 4);
  float*  dinv_p  = (float*) alloc((size_t)NND * 4);
  int4*   csr     = (int4*)  alloc((size_t)NED * 16);
  ushort* b1hi    = (ushort*)alloc((size_t)FIN * HID * 2);
  ushort* b1lo    = (ushort*)alloc((size_t)FIN * HID * 2);
  ushort* b2hi    = (ushort*)alloc((size_t)HID * ENC * 2);
  ushort* b2lo    = (ushort*)alloc((size_t)HID * ENC * 2);
  float*  h_lin   = (float*) alloc((size_t)NND * HID * 4);       // reused as h2
  ushort* hhs     = (ushort*)alloc((size_t)2 * NND * 2 * HID * 2); // split rows

  float* h2 = h_lin;   // node-interleaved [N][128]: g | p

  float* out_emb = (float*)d_out;
  float* out_cls = (float*)d_out + (size_t)NND * ENC;
  float* out_dom = (float*)d_out + (size_t)NND * (ENC + NCLS);

  // ---- graph preprocessing ----
  hipMemsetAsync(deg_cnt, 0, (size_t)NND * 4, stream);
  hipMemsetAsync(cursor,  0, (size_t)NND * 4, stream);
  hipMemsetAsync(degp,    0, (size_t)NND * 4, stream);

  k_deg<<<NED / 256, 256, 0, stream>>>(dst, ppmi, deg_cnt, degp);
  k_dinv<<<(NND + 255) / 256, 256, 0, stream>>>(deg_cnt, degp, dinv_g, dinv_p);
  k_scan_a<<<NBS, SCAN_BS, 0, stream>>>(deg_cnt, psum);
  k_scan_b<<<1, 512, 0, stream>>>(psum);
  k_scan_c<<<NBS, SCAN_BS, 0, stream>>>(deg_cnt, psum, row_ptr);
  k_scatter<<<NED / 256, 256, 0, stream>>>(src, dst, ppmi, row_ptr, cursor,
                                           dinv_g, dinv_p, csr);

  // ---- weight preconversion (tiny) ----
  k_bprep<HID><<<(FIN * HID + 255) / 256, 256, 0, stream>>>(W1, b1hi, b1lo, FIN);
  k_bprep<ENC><<<(HID * ENC + 255) / 256, 256, 0, stream>>>(W2, b2hi, b2lo, HID);

  // ---- encoder ----
  // h_lin = x @ W1   (M=100000, K=512, Nc=128), 2x2 waves, runtime A-split
  gemm_split<2, 2, 0, 0><<<(NND + 127) / 128, 256, 0, stream>>>(
      x, b1hi, b1lo, h_lin, NND, FIN, HID);
  k_agg1<<<(NND * 64) / 256, 256, 0, stream>>>(h_lin, row_ptr, csr,
                                               dinv_g, dinv_p, b1, hhs);
  // h2 = [hg;hp] @ W2 (M=2N, K=128, Nc=64), 4x1 waves, pre-split A,
  // node-interleaved output
  gemm_split<4, 1, 1, 1><<<(2 * NND + 255) / 256, 256, 0, stream>>>(
      hhs, b2hi, b2lo, h2, 2 * NND, HID, ENC);
  k_agg2<<<(NND * 64) / 256, 256, 0, stream>>>(h2, row_ptr, csr,
                                               dinv_g, dinv_p, b2, att_w, att_b, out_emb);

  // ---- heads ----
  k_head<<<(NND + 127) / 128, 128, 0, stream>>>(out_emb, cls_w, cls_b, dw1, db1,
                                                dw2, db2, out_cls, out_dom);
}

// Round 5
// 692.921 us; speedup vs baseline: 1.3759x; 1.0889x over previous
//
#include <hip/hip_runtime.h>
#include <math.h>
#include <stdint.h>

#define NND  100000   // nodes
#define NED  1600000  // edges (without self loops)
#define FIN  512
#define HID  128
#define ENC  64
#define NCLS 10
#define DOM  40

#define SCAN_BS 256
#define NBS ((NND + SCAN_BS - 1) / SCAN_BS)   // 391

typedef __attribute__((ext_vector_type(8))) short short8v;
typedef __attribute__((ext_vector_type(4))) float f32x4;
typedef __attribute__((ext_vector_type(4))) unsigned int uint4v;

// ---------------- degree / norm ----------------

__global__ void k_deg(const int* __restrict__ dst, const float* __restrict__ ppmi,
                      int* __restrict__ deg_cnt, float* __restrict__ degp) {
  int e = blockIdx.x * blockDim.x + threadIdx.x;
  if (e >= NED) return;
  int d = dst[e];
  atomicAdd(&deg_cnt[d], 1);
  atomicAdd(&degp[d], ppmi[e]);
}

__global__ void k_dinv(const int* __restrict__ deg_cnt, const float* __restrict__ degp,
                       float* __restrict__ dinv_g, float* __restrict__ dinv_p) {
  int i = blockIdx.x * blockDim.x + threadIdx.x;
  if (i >= NND) return;
  dinv_g[i] = 1.0f / sqrtf((float)deg_cnt[i] + 1.0f);
  dinv_p[i] = 1.0f / sqrtf(degp[i] + 1.0f);
}

// ---------------- 3-kernel exclusive scan (row_ptr) ----------------

__global__ void k_scan_a(const int* __restrict__ deg, int* __restrict__ psum) {
  __shared__ int s[SCAN_BS];
  int t = threadIdx.x, i = blockIdx.x * SCAN_BS + t;
  s[t] = (i < NND) ? deg[i] : 0;
  __syncthreads();
  for (int o = SCAN_BS / 2; o; o >>= 1) {
    if (t < o) s[t] += s[t + o];
    __syncthreads();
  }
  if (t == 0) psum[blockIdx.x] = s[0];
}

__global__ void k_scan_b(int* __restrict__ psum) {
  __shared__ int s[512];
  int t = threadIdx.x;
  int v = (t < NBS) ? psum[t] : 0;
  s[t] = v;
  __syncthreads();
  for (int o = 1; o < 512; o <<= 1) {
    int add = (t >= o) ? s[t - o] : 0;
    __syncthreads();
    s[t] += add;
    __syncthreads();
  }
  if (t < NBS) psum[t] = s[t] - v;   // exclusive
}

__global__ void k_scan_c(const int* __restrict__ deg, const int* __restrict__ psum,
                         int* __restrict__ row_ptr) {
  __shared__ int s[SCAN_BS];
  int t = threadIdx.x, i = blockIdx.x * SCAN_BS + t;
  int v = (i < NND) ? deg[i] : 0;
  s[t] = v;
  __syncthreads();
  for (int o = 1; o < SCAN_BS; o <<= 1) {
    int add = (t >= o) ? s[t - o] : 0;
    __syncthreads();
    s[t] += add;
    __syncthreads();
  }
  if (i < NND) row_ptr[i] = psum[blockIdx.x] + s[t] - v;
  if (i == NND - 1) row_ptr[NND] = psum[blockIdx.x] + s[t];
}

// ---------------- CSR scatter: packed 16B record {src, gn, pn, 0} -------------

__global__ void k_scatter(const int* __restrict__ src, const int* __restrict__ dst,
                          const float* __restrict__ ppmi,
                          const int* __restrict__ row_ptr, int* __restrict__ cursor,
                          const float* __restrict__ dinv_g, const float* __restrict__ dinv_p,
                          int4* __restrict__ csr) {
  int e = blockIdx.x * blockDim.x + threadIdx.x;
  if (e >= NED) return;
  int s = src[e], d = dst[e];
  int pos = row_ptr[d] + atomicAdd(&cursor[d], 1);
  int4 rec;
  rec.x = s;
  rec.y = __float_as_int(dinv_g[s] * dinv_g[d]);
  rec.z = __float_as_int(dinv_p[s] * ppmi[e] * dinv_p[d]);
  rec.w = 0;
  csr[pos] = rec;
}

// ---------------- B preconversion to split-bf16 fragment layout --------------
// B[K][Nc] fp32 -> Bhi/Blo [K/8][Nc][8] bf16 (truncated hi + truncated residual)

template<int NC>
__global__ void k_bprep(const float* __restrict__ B, ushort* __restrict__ bhi,
                        ushort* __restrict__ blo, int K) {
  int id = blockIdx.x * 256 + threadIdx.x;
  if (id >= K * NC) return;
  int k = id / NC, c = id % NC;
  float x = B[id];
  unsigned int u = __float_as_uint(x);
  ushort h = (ushort)(u >> 16);
  float lo = x - __uint_as_float(u & 0xffff0000u);
  ushort l = (ushort)(__float_as_uint(lo) >> 16);
  size_t o = ((size_t)(k >> 3) * NC + c) * 8 + (k & 7);
  bhi[o] = h;
  blo[o] = l;
}

// ---------------- split helpers ----------------

__device__ inline void split8(const float4 a, const float4 b,
                              short8v& hi, short8v& lo) {
  float f[8] = {a.x, a.y, a.z, a.w, b.x, b.y, b.z, b.w};
  uint4v H, L;
#pragma unroll
  for (int i = 0; i < 4; ++i) {
    unsigned int u0 = __float_as_uint(f[2 * i]);
    unsigned int u1 = __float_as_uint(f[2 * i + 1]);
    H[i] = (u0 >> 16) | (u1 & 0xffff0000u);
    float l0 = f[2 * i]     - __uint_as_float(u0 & 0xffff0000u);
    float l1 = f[2 * i + 1] - __uint_as_float(u1 & 0xffff0000u);
    L[i] = (__float_as_uint(l0) >> 16) | (__float_as_uint(l1) & 0xffff0000u);
  }
  hi = __builtin_bit_cast(short8v, H);
  lo = __builtin_bit_cast(short8v, L);
}

__device__ inline void split1(float x, ushort& h, ushort& l) {
  unsigned int u = __float_as_uint(x);
  h = (ushort)(u >> 16);
  float r = x - __uint_as_float(u & 0xffff0000u);
  l = (ushort)(__float_as_uint(r) >> 16);
}

// ---------------- GEMM1: h_lin = x @ W1, LDS-staged split-bf16 MFMA ----------
// M=NND, K=FIN=512, Nc=HID=128. Tile 128x128, BK=32, 4 waves (2x2), wave 64x64.
// A staged fp32 -> LDS (double-buffered) via global_load_lds width=16.
// LDS tile [128][32] fp32; 16B-chunk XOR swizzle (chunk ^= row&7) applied on
// the GLOBAL source and on the ds_read (both-sides involution, LDS dest linear).

__device__ inline void gload_lds16(const float* gp, float* lp) {
  __builtin_amdgcn_global_load_lds(
      (const __attribute__((address_space(1))) void*)gp,
      (__attribute__((address_space(3))) void*)lp, 16, 0, 0);
}

__global__ __launch_bounds__(256, 2) void gemm1_lds(
    const float* __restrict__ A, const ushort* __restrict__ Bhi,
    const ushort* __restrict__ Blo, float* __restrict__ C) {
  __shared__ float At[2][128 * 32];
  const int tid = threadIdx.x;
  const int lane = tid & 63;
  const int w = tid >> 6;
  const int wr = w >> 1, wc = w & 1;
  const int g = lane >> 4;
  const int l16 = lane & 15;
  const int row_base = blockIdx.x * 128;

  // staging source addresses (4 issues x 16B per lane per k-step)
  size_t srow[4]; int scol[4];
  {
    int e = w * 256 + lane * 4;     // float index within 128x32 tile, issue 0
#pragma unroll
    for (int i = 0; i < 4; ++i) {
      int ee = e + i * 1024;
      int r = ee >> 5;              // tile row
      int chunk_lds = (ee >> 2) & 7;
      int chunk_g = chunk_lds ^ (r & 7);  // pre-swizzled global chunk
      int rr = row_base + r; if (rr >= NND) rr = NND - 1;   // clamped, safe
      srow[i] = (size_t)rr * FIN;
      scol[i] = chunk_g * 4;
    }
  }

  int coln[4];
#pragma unroll
  for (int n = 0; n < 4; ++n) coln[n] = wc * 64 + n * 16 + l16;
  int arow_l[4];
#pragma unroll
  for (int m = 0; m < 4; ++m) arow_l[m] = wr * 64 + m * 16 + l16;

  f32x4 acc[4][4] = {};

  // prologue: stage k-tile 0 into buf 0
#pragma unroll
  for (int i = 0; i < 4; ++i)
    gload_lds16(A + srow[i] + 0 + scol[i], &At[0][w * 256 + i * 1024]);
  __syncthreads();   // drains vmcnt -> buf0 ready

  for (int t = 0; t < FIN / 32; ++t) {
    const int cur = t & 1;
    if (t + 1 < FIN / 32) {
      const int k0n = (t + 1) * 32;
#pragma unroll
      for (int i = 0; i < 4; ++i)
        gload_lds16(A + srow[i] + k0n + scol[i], &At[cur ^ 1][w * 256 + i * 1024]);
    }

    short8v ah[4], al[4];
#pragma unroll
    for (int m = 0; m < 4; ++m) {
      int r = arow_l[m];
      int c0 = (((g * 2)     ^ (r & 7)) << 2);
      int c1 = (((g * 2 + 1) ^ (r & 7)) << 2);
      float4 a0 = *(const float4*)&At[cur][r * 32 + c0];
      float4 a1 = *(const float4*)&At[cur][r * 32 + c1];
      split8(a0, a1, ah[m], al[m]);
    }

    short8v bh[4], bl[4];
    const int kc = t * 4 + g;
#pragma unroll
    for (int n = 0; n < 4; ++n) {
      size_t off = ((size_t)kc * HID + coln[n]) * 8;
      bh[n] = *(const short8v*)(Bhi + off);
      bl[n] = *(const short8v*)(Blo + off);
    }

#pragma unroll
    for (int m = 0; m < 4; ++m)
#pragma unroll
      for (int n = 0; n < 4; ++n) {
        acc[m][n] = __builtin_amdgcn_mfma_f32_16x16x32_bf16(ah[m], bh[n], acc[m][n], 0, 0, 0);
        acc[m][n] = __builtin_amdgcn_mfma_f32_16x16x32_bf16(al[m], bh[n], acc[m][n], 0, 0, 0);
        acc[m][n] = __builtin_amdgcn_mfma_f32_16x16x32_bf16(ah[m], bl[n], acc[m][n], 0, 0, 0);
      }

    __syncthreads();   // all waves done reading buf[cur]; next stage landed
  }

  // C/D layout: col = lane&15, row = (lane>>4)*4 + reg
  // NOTE: wave row offset wr*64 must be included here (R4 bug: it wasn't).
#pragma unroll
  for (int m = 0; m < 4; ++m)
#pragma unroll
    for (int i = 0; i < 4; ++i) {
      int r = row_base + wr * 64 + m * 16 + g * 4 + i;
      if (r < NND) {
#pragma unroll
        for (int n = 0; n < 4; ++n)
          C[(size_t)r * HID + coln[n]] = acc[m][n][i];
      }
    }
}

// ---------------- split-bf16 MFMA GEMM (register A path, used for GEMM2) -----
// ASPLIT=1: A rows are [hi bf16 x K | lo bf16 x K] (2K ushorts per row).
// MODE 1: rows [0,NND) -> h2[r][c], rows [NND,2NND) -> h2[r-NND][64+c].

template<int WR, int WC, int MODE, int ASPLIT>
__global__ __launch_bounds__(256, 2) void gemm_split(
    const void* __restrict__ Av, const ushort* __restrict__ Bhi,
    const ushort* __restrict__ Blo, float* __restrict__ C,
    int M, int K, int Nc) {
  const int lane = threadIdx.x & 63;
  const int w = threadIdx.x >> 6;
  const int wr = w / WC, wc = w % WC;
  const int g = lane >> 4;
  const int l16 = lane & 15;
  const int row_base = blockIdx.x * (WR * 64) + wr * 64;

  size_t arow[4];
#pragma unroll
  for (int m = 0; m < 4; ++m) {
    int r = row_base + m * 16 + l16;
    if (r >= M) r = M - 1;
    arow[m] = (size_t)r * (ASPLIT ? 2 * K : K);
  }
  int coln[4];
#pragma unroll
  for (int n = 0; n < 4; ++n) coln[n] = wc * 64 + n * 16 + l16;

  f32x4 acc[4][4] = {};

  for (int k0 = 0; k0 < K; k0 += 32) {
    short8v ah[4], al[4];
    if constexpr (ASPLIT) {
      const ushort* As = (const ushort*)Av;
#pragma unroll
      for (int m = 0; m < 4; ++m) {
        const ushort* p = As + arow[m] + k0 + g * 8;
        ah[m] = *(const short8v*)p;
        al[m] = *(const short8v*)(p + K);
      }
    } else {
      const float* A = (const float*)Av;
      float4 a0[4], a1[4];
#pragma unroll
      for (int m = 0; m < 4; ++m) {
        const float* p = A + arow[m] + k0 + g * 8;
        a0[m] = *(const float4*)p;
        a1[m] = *(const float4*)(p + 4);
      }
#pragma unroll
      for (int m = 0; m < 4; ++m) split8(a0[m], a1[m], ah[m], al[m]);
    }
    short8v bh[4], bl[4];
    const int kc = (k0 >> 3) + g;
#pragma unroll
    for (int n = 0; n < 4; ++n) {
      size_t off = ((size_t)kc * Nc + coln[n]) * 8;
      bh[n] = *(const short8v*)(Bhi + off);
      bl[n] = *(const short8v*)(Blo + off);
    }
#pragma unroll
    for (int m = 0; m < 4; ++m)
#pragma unroll
      for (int n = 0; n < 4; ++n) {
        acc[m][n] = __builtin_amdgcn_mfma_f32_16x16x32_bf16(ah[m], bh[n], acc[m][n], 0, 0, 0);
        acc[m][n] = __builtin_amdgcn_mfma_f32_16x16x32_bf16(al[m], bh[n], acc[m][n], 0, 0, 0);
        acc[m][n] = __builtin_amdgcn_mfma_f32_16x16x32_bf16(ah[m], bl[n], acc[m][n], 0, 0, 0);
      }
  }

#pragma unroll
  for (int m = 0; m < 4; ++m)
#pragma unroll
    for (int i = 0; i < 4; ++i) {
      int r = row_base + m * 16 + g * 4 + i;
      if (r < M) {
#pragma unroll
        for (int n = 0; n < 4; ++n) {
          int c = coln[n];
          size_t o;
          if (MODE == 0) o = (size_t)r * Nc + c;
          else o = (r < NND) ? ((size_t)r * 128 + c)
                             : ((size_t)(r - NND) * 128 + 64 + c);
          C[o] = acc[m][n][i];
        }
      }
    }
}

// ---------------- layer-1 aggregation, both norms ----------------
// one wave per node; lanes 0-31 even edges, 32-63 odd edges; float4/lane.
// outputs relu(agg+b1) as split-bf16 rows [hi128|lo128] (hg row wid, hp row NND+wid)

__global__ __launch_bounds__(256) void k_agg1(
    const float* __restrict__ hlin, const int* __restrict__ row_ptr,
    const int4* __restrict__ csr,
    const float* __restrict__ dinv_g, const float* __restrict__ dinv_p,
    const float* __restrict__ b1, ushort* __restrict__ hhs) {
  int wid = (blockIdx.x * blockDim.x + threadIdx.x) >> 6;
  int lane = threadIdx.x & 63;
  if (wid >= NND) return;
  const int half = lane >> 5;
  const int l5 = lane & 31;
  float sg = dinv_g[wid]; sg *= sg;       // self-loop norm = dinv^2
  float sp = dinv_p[wid]; sp *= sp;

  float agx = 0.f, agy = 0.f, agz = 0.f, agw = 0.f;
  float apx = 0.f, apy = 0.f, apz = 0.f, apw = 0.f;
  if (half == 0) {
    float4 v = *(const float4*)(hlin + (size_t)wid * HID + 4 * l5);
    agx = v.x * sg; agy = v.y * sg; agz = v.z * sg; agw = v.w * sg;
    apx = v.x * sp; apy = v.y * sp; apz = v.z * sp; apw = v.w * sp;
  }

  int e0 = row_ptr[wid], e1 = row_ptr[wid + 1];
  int k = e0 + half;
  if (k < e1) {
    int4 rec = csr[k];
    while (true) {
      int kn = k + 2;
      int4 nrec = csr[kn < e1 ? kn : k];        // clamped prefetch
      float wg = __int_as_float(rec.y);
      float wp = __int_as_float(rec.z);
      float4 u = *(const float4*)(hlin + (size_t)rec.x * HID + 4 * l5);
      agx = fmaf(u.x, wg, agx); agy = fmaf(u.y, wg, agy);
      agz = fmaf(u.z, wg, agz); agw = fmaf(u.w, wg, agw);
      apx = fmaf(u.x, wp, apx); apy = fmaf(u.y, wp, apy);
      apz = fmaf(u.z, wp, apz); apw = fmaf(u.w, wp, apw);
      if (kn >= e1) break;
      k = kn; rec = nrec;
    }
  }

  agx += __shfl_xor(agx, 32); agy += __shfl_xor(agy, 32);
  agz += __shfl_xor(agz, 32); agw += __shfl_xor(agw, 32);
  apx += __shfl_xor(apx, 32); apy += __shfl_xor(apy, 32);
  apz += __shfl_xor(apz, 32); apw += __shfl_xor(apw, 32);

  float4 bb = *(const float4*)(b1 + 4 * l5);
  float r0, r1, r2, r3;
  if (half == 0) { r0 = agx + bb.x; r1 = agy + bb.y; r2 = agz + bb.z; r3 = agw + bb.w; }
  else           { r0 = apx + bb.x; r1 = apy + bb.y; r2 = apz + bb.z; r3 = apw + bb.w; }
  r0 = fmaxf(r0, 0.f); r1 = fmaxf(r1, 0.f); r2 = fmaxf(r2, 0.f); r3 = fmaxf(r3, 0.f);

  ushort4 hv, lv;
  split1(r0, hv.x, lv.x); split1(r1, hv.y, lv.y);
  split1(r2, hv.z, lv.z); split1(r3, hv.w, lv.w);
  size_t rowbase = (size_t)(half ? NND + wid : wid) * (2 * HID);
  *(ushort4*)(hhs + rowbase + 4 * l5) = hv;           // hi block [0,128)
  *(ushort4*)(hhs + rowbase + HID + 4 * l5) = lv;     // lo block [128,256)
}

// ---------------- layer-2 aggregation + attention softmax -> emb --------------
// h2 node-interleaved: h2[node][0:64]=g, [64:128]=p.  One wave per node.
// lane = (edge parity ep)<<5 | (branch q)<<4 | t;  float4 covers feats 4t..4t+3.

__global__ __launch_bounds__(256) void k_agg2(
    const float* __restrict__ h2, const int* __restrict__ row_ptr,
    const int4* __restrict__ csr,
    const float* __restrict__ dinv_g, const float* __restrict__ dinv_p,
    const float* __restrict__ b2, const float* __restrict__ att_w,
    const float* __restrict__ att_b, float* __restrict__ out_emb) {
  int wid = (blockIdx.x * blockDim.x + threadIdx.x) >> 6;
  int lane = threadIdx.x & 63;
  if (wid >= NND) return;
  const int ep = lane >> 5;
  const int q  = (lane >> 4) & 1;
  const int t  = lane & 15;
  float sg = dinv_g[wid]; sg *= sg;
  float sp = dinv_p[wid]; sp *= sp;
  const float sw = q ? sp : sg;

  float ax = 0.f, ay = 0.f, az = 0.f, azw = 0.f;
  if (ep == 0) {
    float4 v = *(const float4*)(h2 + (size_t)wid * 128 + q * 64 + 4 * t);
    ax = v.x * sw; ay = v.y * sw; az = v.z * sw; azw = v.w * sw;
  }

  int e0 = row_ptr[wid], e1 = row_ptr[wid + 1];
  int k = e0 + ep;
  if (k < e1) {
    int4 rec = csr[k];
    while (true) {
      int kn = k + 2;
      int4 nrec = csr[kn < e1 ? kn : k];
      float w = __int_as_float(q ? rec.z : rec.y);
      float4 u = *(const float4*)(h2 + (size_t)rec.x * 128 + q * 64 + 4 * t);
      ax = fmaf(u.x, w, ax); ay = fmaf(u.y, w, ay);
      az = fmaf(u.z, w, az); azw = fmaf(u.w, w, azw);
      if (kn >= e1) break;
      k = kn; rec = nrec;
    }
  }

  ax += __shfl_xor(ax, 32); ay += __shfl_xor(ay, 32);
  az += __shfl_xor(az, 32); azw += __shfl_xor(azw, 32);

  float4 bb = *(const float4*)(b2 + 4 * t);
  float vx = ax + bb.x, vy = ay + bb.y, vz = az + bb.z, vw = azw + bb.w;

  float4 aw4 = *(const float4*)(att_w + 4 * t);
  float part = vx * aw4.x + vy * aw4.y + vz * aw4.z + vw * aw4.w;
  part += __shfl_xor(part, 8);
  part += __shfl_xor(part, 4);
  part += __shfl_xor(part, 2);
  part += __shfl_xor(part, 1);
  float other = __shfl_xor(part, 16);
  float ab = att_b[0];
  float lg = (q ? other : part) + ab;
  float lp = (q ? part : other) + ab;
  float mx = fmaxf(lg, lp);
  float egv = expf(lg - mx), epv = expf(lp - mx);
  float wsm = egv / (egv + epv);        // weight of g branch

  float ox = __shfl_xor(vx, 16);
  float oy = __shfl_xor(vy, 16);
  float oz = __shfl_xor(vz, 16);
  float ow = __shfl_xor(vw, 16);
  if (lane < 16) {                       // val = gv, other = pv
    float4 o;
    o.x = wsm * vx + (1.f - wsm) * ox;
    o.y = wsm * vy + (1.f - wsm) * oy;
    o.z = wsm * vz + (1.f - wsm) * oz;
    o.w = wsm * vw + (1.f - wsm) * ow;
    *(float4*)(out_emb + (size_t)wid * 64 + 4 * t) = o;
  }
}

// ---------------- class + domain heads --------------

__global__ __launch_bounds__(128) void k_head(
    const float* __restrict__ emb,
    const float* __restrict__ cls_w, const float* __restrict__ cls_b,
    const float* __restrict__ dw1, const float* __restrict__ db1,
    const float* __restrict__ dw2, const float* __restrict__ db2,
    float* __restrict__ out_cls, float* __restrict__ out_dom) {
  __shared__ float se[128 * 65];
  const int t = threadIdx.x;
  const int base = blockIdx.x * 128;
  for (int c = 0; c < 64; ++c) {
    int idx = c * 128 + t;
    int nl = idx >> 6, k = idx & 63;
    size_t g = (size_t)base * ENC + idx;
    float v = (g < (size_t)NND * ENC) ? emb[g] : 0.f;
    se[nl * 65 + k] = v;
  }
  __syncthreads();

  int node = base + t;
  float c[NCLS], hd[DOM];
#pragma unroll
  for (int j = 0; j < NCLS; ++j) c[j] = cls_b[j];
#pragma unroll
  for (int j = 0; j < DOM; ++j) hd[j] = db1[j];

  for (int k = 0; k < ENC; ++k) {
    float ev = se[t * 65 + k];
#pragma unroll
    for (int j = 0; j < NCLS; ++j) c[j] += ev * cls_w[k * NCLS + j];
#pragma unroll
    for (int j = 0; j < DOM; ++j) hd[j] += ev * dw1[k * DOM + j];
  }
  float d0 = db2[0], d1 = db2[1];
#pragma unroll
  for (int j = 0; j < DOM; ++j) {
    float hv = fmaxf(hd[j], 0.f);
    d0 += hv * dw2[j * 2];
    d1 += hv * dw2[j * 2 + 1];
  }
  if (node < NND) {
#pragma unroll
    for (int j = 0; j < NCLS; ++j) out_cls[(size_t)node * NCLS + j] = c[j];
    out_dom[(size_t)node * 2]     = d0;
    out_dom[(size_t)node * 2 + 1] = d1;
  }
}

// ---------------- host ----------------

extern "C" void kernel_launch(void* const* d_in, const int* in_sizes, int n_in,
                              void* d_out, int out_size, void* d_ws, size_t ws_size,
                              hipStream_t stream) {
  const float* x     = (const float*)d_in[0];
  const int*   ei    = (const int*)d_in[1];
  const float* ppmi  = (const float*)d_in[2];
  const float* W1    = (const float*)d_in[4];
  const float* b1    = (const float*)d_in[5];
  const float* W2    = (const float*)d_in[6];
  const float* b2    = (const float*)d_in[7];
  const float* att_w = (const float*)d_in[8];
  const float* att_b = (const float*)d_in[9];
  const float* cls_w = (const float*)d_in[10];
  const float* cls_b = (const float*)d_in[11];
  const float* dw1   = (const float*)d_in[12];
  const float* db1   = (const float*)d_in[13];
  const float* dw2   = (const float*)d_in[14];
  const float* db2   = (const float*)d_in[15];

  const int* src = ei;
  const int* dst = ei + NED;

  uintptr_t p = (uintptr_t)d_ws;
  auto alloc = [&](size_t bytes) -> void* {
    void* r = (void*)p;
    p += (bytes + 255) & ~(size_t)255;
    return r;
  };
  int*    deg_cnt = (int*)   alloc((size_t)NND * 4);
  int*    cursor  = (int*)   alloc((size_t)NND * 4);
  float*  degp    = (float*) alloc((size_t)NND * 4);
  int*    row_ptr = (int*)   alloc((size_t)(NND + 1) * 4);
  int*    psum    = (int*)   alloc((size_t)NBS * 4);
  float*  dinv_g  = (float*) alloc((size_t)NND * 4);
  float*  dinv_p  = (float*) alloc((size_t)NND * 4);
  int4*   csr     = (int4*)  alloc((size_t)NED * 16);
  ushort* b1hi    = (ushort*)alloc((size_t)FIN * HID * 2);
  ushort* b1lo    = (ushort*)alloc((size_t)FIN * HID * 2);
  ushort* b2hi    = (ushort*)alloc((size_t)HID * ENC * 2);
  ushort* b2lo    = (ushort*)alloc((size_t)HID * ENC * 2);
  float*  h_lin   = (float*) alloc((size_t)NND * HID * 4);       // reused as h2
  ushort* hhs     = (ushort*)alloc((size_t)2 * NND * 2 * HID * 2); // split rows

  float* h2 = h_lin;   // node-interleaved [N][128]: g | p

  float* out_emb = (float*)d_out;
  float* out_cls = (float*)d_out + (size_t)NND * ENC;
  float* out_dom = (float*)d_out + (size_t)NND * (ENC + NCLS);

  // ---- graph preprocessing ----
  hipMemsetAsync(deg_cnt, 0, (size_t)NND * 4, stream);
  hipMemsetAsync(cursor,  0, (size_t)NND * 4, stream);
  hipMemsetAsync(degp,    0, (size_t)NND * 4, stream);

  k_deg<<<NED / 256, 256, 0, stream>>>(dst, ppmi, deg_cnt, degp);
  k_dinv<<<(NND + 255) / 256, 256, 0, stream>>>(deg_cnt, degp, dinv_g, dinv_p);
  k_scan_a<<<NBS, SCAN_BS, 0, stream>>>(deg_cnt, psum);
  k_scan_b<<<1, 512, 0, stream>>>(psum);
  k_scan_c<<<NBS, SCAN_BS, 0, stream>>>(deg_cnt, psum, row_ptr);
  k_scatter<<<NED / 256, 256, 0, stream>>>(src, dst, ppmi, row_ptr, cursor,
                                           dinv_g, dinv_p, csr);

  // ---- weight preconversion (tiny) ----
  k_bprep<HID><<<(FIN * HID + 255) / 256, 256, 0, stream>>>(W1, b1hi, b1lo, FIN);
  k_bprep<ENC><<<(HID * ENC + 255) / 256, 256, 0, stream>>>(W2, b2hi, b2lo, HID);

  // ---- encoder ----
  // h_lin = x @ W1   (M=100000, K=512, Nc=128), LDS-staged double-buffered
  gemm1_lds<<<(NND + 127) / 128, 256, 0, stream>>>(x, b1hi, b1lo, h_lin);
  k_agg1<<<(NND * 64) / 256, 256, 0, stream>>>(h_lin, row_ptr, csr,
                                               dinv_g, dinv_p, b1, hhs);
  // h2 = [hg;hp] @ W2 (M=2N, K=128, Nc=64), 4x1 waves, pre-split A,
  // node-interleaved output
  gemm_split<4, 1, 1, 1><<<(2 * NND + 255) / 256, 256, 0, stream>>>(
      hhs, b2hi, b2lo, h2, 2 * NND, HID, ENC);
  k_agg2<<<(NND * 64) / 256, 256, 0, stream>>>(h2, row_ptr, csr,
                                               dinv_g, dinv_p, b2, att_w, att_b, out_emb);

  // ---- heads ----
  k_head<<<(NND + 127) / 128, 128, 0, stream>>>(out_emb, cls_w, cls_b, dw1, db1,
                                                dw2, db2, out_cls, out_dom);
}

// Round 6
// 582.458 us; speedup vs baseline: 1.6369x; 1.1896x over previous
//
#include <hip/hip_runtime.h>
#include <math.h>
#include <stdint.h>

#define NND  100000   // nodes
#define NED  1600000  // edges (without self loops)
#define FIN  512
#define HID  128
#define ENC  64
#define NCLS 10
#define DOM  40

#define SCAN_BS 256
#define NBS ((NND + SCAN_BS - 1) / SCAN_BS)   // 391

typedef __attribute__((ext_vector_type(8))) short short8v;
typedef __attribute__((ext_vector_type(4))) float f32x4;
typedef __attribute__((ext_vector_type(4))) unsigned int uint4v;

// ---------------- degree + rank: ONE packed 64-bit atomic per edge ----------
// packed[d]: bits [40,64) = edge count, bits [0,40) = sum(ppmi) in 2^-30 fixed
// point (ppmi < 1.0, deg <~ 64 -> sum < 2^36: no carry into count field).
// Returned old value yields this edge's rank within its dst row.

__global__ void k_deg_rank(const int* __restrict__ dst, const float* __restrict__ ppmi,
                           unsigned long long* __restrict__ packed,
                           int* __restrict__ rank) {
  int e = blockIdx.x * blockDim.x + threadIdx.x;
  if (e >= NED) return;
  int d = dst[e];
  unsigned int fx = (unsigned int)(ppmi[e] * 1073741824.0f + 0.5f);  // 2^30 scale
  unsigned long long v = (1ull << 40) | (unsigned long long)fx;
  unsigned long long old = atomicAdd(&packed[d], v);
  rank[e] = (int)(old >> 40);
}

__global__ void k_dinv(const unsigned long long* __restrict__ packed,
                       float* __restrict__ dinv_g, float* __restrict__ dinv_p) {
  int i = blockIdx.x * blockDim.x + threadIdx.x;
  if (i >= NND) return;
  unsigned long long pk = packed[i];
  float cnt = (float)(unsigned int)(pk >> 40);
  float dp  = (float)(pk & 0xFFFFFFFFFFull) * (1.0f / 1073741824.0f);
  // self-loop contributes +1 to both degree sums
  dinv_g[i] = 1.0f / sqrtf(cnt + 1.0f);
  dinv_p[i] = 1.0f / sqrtf(dp + 1.0f);
}

// ---------------- 3-kernel exclusive scan (row_ptr) over packed counts -------

__global__ void k_scan_a(const unsigned long long* __restrict__ packed,
                         int* __restrict__ psum) {
  __shared__ int s[SCAN_BS];
  int t = threadIdx.x, i = blockIdx.x * SCAN_BS + t;
  s[t] = (i < NND) ? (int)(packed[i] >> 40) : 0;
  __syncthreads();
  for (int o = SCAN_BS / 2; o; o >>= 1) {
    if (t < o) s[t] += s[t + o];
    __syncthreads();
  }
  if (t == 0) psum[blockIdx.x] = s[0];
}

__global__ void k_scan_b(int* __restrict__ psum) {
  __shared__ int s[512];
  int t = threadIdx.x;
  int v = (t < NBS) ? psum[t] : 0;
  s[t] = v;
  __syncthreads();
  for (int o = 1; o < 512; o <<= 1) {
    int add = (t >= o) ? s[t - o] : 0;
    __syncthreads();
    s[t] += add;
    __syncthreads();
  }
  if (t < NBS) psum[t] = s[t] - v;   // exclusive
}

__global__ void k_scan_c(const unsigned long long* __restrict__ packed,
                         const int* __restrict__ psum, int* __restrict__ row_ptr) {
  __shared__ int s[SCAN_BS];
  int t = threadIdx.x, i = blockIdx.x * SCAN_BS + t;
  int v = (i < NND) ? (int)(packed[i] >> 40) : 0;
  s[t] = v;
  __syncthreads();
  for (int o = 1; o < SCAN_BS; o <<= 1) {
    int add = (t >= o) ? s[t - o] : 0;
    __syncthreads();
    s[t] += add;
    __syncthreads();
  }
  if (i < NND) row_ptr[i] = psum[blockIdx.x] + s[t] - v;
  if (i == NND - 1) row_ptr[NND] = psum[blockIdx.x] + s[t];
}

// ---------------- CSR scatter: atomic-free (pos = row_ptr[d] + rank[e]) ------

__global__ void k_scatter(const int* __restrict__ src, const int* __restrict__ dst,
                          const float* __restrict__ ppmi,
                          const int* __restrict__ row_ptr, const int* __restrict__ rank,
                          const float* __restrict__ dinv_g, const float* __restrict__ dinv_p,
                          int4* __restrict__ csr) {
  int e = blockIdx.x * blockDim.x + threadIdx.x;
  if (e >= NED) return;
  int s = src[e], d = dst[e];
  int pos = row_ptr[d] + rank[e];
  int4 rec;
  rec.x = s;
  rec.y = __float_as_int(dinv_g[s] * dinv_g[d]);
  rec.z = __float_as_int(dinv_p[s] * ppmi[e] * dinv_p[d]);
  rec.w = 0;
  csr[pos] = rec;
}

// ---------------- B preconversion to split-bf16 fragment layout --------------
// B[K][Nc] fp32 -> Bhi/Blo [K/8][Nc][8] bf16 (truncated hi + truncated residual)

template<int NC>
__global__ void k_bprep(const float* __restrict__ B, ushort* __restrict__ bhi,
                        ushort* __restrict__ blo, int K) {
  int id = blockIdx.x * 256 + threadIdx.x;
  if (id >= K * NC) return;
  int k = id / NC, c = id % NC;
  float x = B[id];
  unsigned int u = __float_as_uint(x);
  ushort h = (ushort)(u >> 16);
  float lo = x - __uint_as_float(u & 0xffff0000u);
  ushort l = (ushort)(__float_as_uint(lo) >> 16);
  size_t o = ((size_t)(k >> 3) * NC + c) * 8 + (k & 7);
  bhi[o] = h;
  blo[o] = l;
}

// ---------------- split helpers ----------------

__device__ inline void split8(const float4 a, const float4 b,
                              short8v& hi, short8v& lo) {
  float f[8] = {a.x, a.y, a.z, a.w, b.x, b.y, b.z, b.w};
  uint4v H, L;
#pragma unroll
  for (int i = 0; i < 4; ++i) {
    unsigned int u0 = __float_as_uint(f[2 * i]);
    unsigned int u1 = __float_as_uint(f[2 * i + 1]);
    H[i] = (u0 >> 16) | (u1 & 0xffff0000u);
    float l0 = f[2 * i]     - __uint_as_float(u0 & 0xffff0000u);
    float l1 = f[2 * i + 1] - __uint_as_float(u1 & 0xffff0000u);
    L[i] = (__float_as_uint(l0) >> 16) | (__float_as_uint(l1) & 0xffff0000u);
  }
  hi = __builtin_bit_cast(short8v, H);
  lo = __builtin_bit_cast(short8v, L);
}

__device__ inline void split1(float x, ushort& h, ushort& l) {
  unsigned int u = __float_as_uint(x);
  h = (ushort)(u >> 16);
  float r = x - __uint_as_float(u & 0xffff0000u);
  l = (ushort)(__float_as_uint(r) >> 16);
}

// ---------------- GEMM1: h_lin = x @ W1, LDS-staged split-bf16 MFMA ----------
// M=NND, K=FIN=512, Nc=HID=128. Tile 128x128, BK=32, 4 waves (2x2), wave 64x64.
// A staged fp32 -> LDS (double-buffered) via global_load_lds width=16.
// LDS tile [128][32] fp32; 16B-chunk XOR swizzle (chunk ^= row&7) applied on
// the GLOBAL source and on the ds_read (both-sides involution, LDS dest linear).

__device__ inline void gload_lds16(const float* gp, float* lp) {
  __builtin_amdgcn_global_load_lds(
      (const __attribute__((address_space(1))) void*)gp,
      (__attribute__((address_space(3))) void*)lp, 16, 0, 0);
}

__global__ __launch_bounds__(256, 2) void gemm1_lds(
    const float* __restrict__ A, const ushort* __restrict__ Bhi,
    const ushort* __restrict__ Blo, float* __restrict__ C) {
  __shared__ float At[2][128 * 32];
  const int tid = threadIdx.x;
  const int lane = tid & 63;
  const int w = tid >> 6;
  const int wr = w >> 1, wc = w & 1;
  const int g = lane >> 4;
  const int l16 = lane & 15;
  const int row_base = blockIdx.x * 128;

  // staging source addresses (4 issues x 16B per lane per k-step)
  size_t srow[4]; int scol[4];
  {
    int e = w * 256 + lane * 4;     // float index within 128x32 tile, issue 0
#pragma unroll
    for (int i = 0; i < 4; ++i) {
      int ee = e + i * 1024;
      int r = ee >> 5;              // tile row
      int chunk_lds = (ee >> 2) & 7;
      int chunk_g = chunk_lds ^ (r & 7);  // pre-swizzled global chunk
      int rr = row_base + r; if (rr >= NND) rr = NND - 1;   // clamped, safe
      srow[i] = (size_t)rr * FIN;
      scol[i] = chunk_g * 4;
    }
  }

  int coln[4];
#pragma unroll
  for (int n = 0; n < 4; ++n) coln[n] = wc * 64 + n * 16 + l16;
  int arow_l[4];
#pragma unroll
  for (int m = 0; m < 4; ++m) arow_l[m] = wr * 64 + m * 16 + l16;

  f32x4 acc[4][4] = {};

  // prologue: stage k-tile 0 into buf 0
#pragma unroll
  for (int i = 0; i < 4; ++i)
    gload_lds16(A + srow[i] + 0 + scol[i], &At[0][w * 256 + i * 1024]);
  __syncthreads();   // drains vmcnt -> buf0 ready

  for (int t = 0; t < FIN / 32; ++t) {
    const int cur = t & 1;
    if (t + 1 < FIN / 32) {
      const int k0n = (t + 1) * 32;
#pragma unroll
      for (int i = 0; i < 4; ++i)
        gload_lds16(A + srow[i] + k0n + scol[i], &At[cur ^ 1][w * 256 + i * 1024]);
    }

    short8v ah[4], al[4];
#pragma unroll
    for (int m = 0; m < 4; ++m) {
      int r = arow_l[m];
      int c0 = (((g * 2)     ^ (r & 7)) << 2);
      int c1 = (((g * 2 + 1) ^ (r & 7)) << 2);
      float4 a0 = *(const float4*)&At[cur][r * 32 + c0];
      float4 a1 = *(const float4*)&At[cur][r * 32 + c1];
      split8(a0, a1, ah[m], al[m]);
    }

    short8v bh[4], bl[4];
    const int kc = t * 4 + g;
#pragma unroll
    for (int n = 0; n < 4; ++n) {
      size_t off = ((size_t)kc * HID + coln[n]) * 8;
      bh[n] = *(const short8v*)(Bhi + off);
      bl[n] = *(const short8v*)(Blo + off);
    }

#pragma unroll
    for (int m = 0; m < 4; ++m)
#pragma unroll
      for (int n = 0; n < 4; ++n) {
        acc[m][n] = __builtin_amdgcn_mfma_f32_16x16x32_bf16(ah[m], bh[n], acc[m][n], 0, 0, 0);
        acc[m][n] = __builtin_amdgcn_mfma_f32_16x16x32_bf16(al[m], bh[n], acc[m][n], 0, 0, 0);
        acc[m][n] = __builtin_amdgcn_mfma_f32_16x16x32_bf16(ah[m], bl[n], acc[m][n], 0, 0, 0);
      }

    __syncthreads();   // all waves done reading buf[cur]; next stage landed
  }

  // C/D layout: col = lane&15, row = (lane>>4)*4 + reg (wave offset wr*64 included)
#pragma unroll
  for (int m = 0; m < 4; ++m)
#pragma unroll
    for (int i = 0; i < 4; ++i) {
      int r = row_base + wr * 64 + m * 16 + g * 4 + i;
      if (r < NND) {
#pragma unroll
        for (int n = 0; n < 4; ++n)
          C[(size_t)r * HID + coln[n]] = acc[m][n][i];
      }
    }
}

// ---------------- split-bf16 MFMA GEMM (register A path, used for GEMM2) -----
// ASPLIT=1: A rows are [hi bf16 x K | lo bf16 x K] (2K ushorts per row).
// MODE 1: rows [0,NND) -> h2[r][c], rows [NND,2NND) -> h2[r-NND][64+c].

template<int WR, int WC, int MODE, int ASPLIT>
__global__ __launch_bounds__(256, 2) void gemm_split(
    const void* __restrict__ Av, const ushort* __restrict__ Bhi,
    const ushort* __restrict__ Blo, float* __restrict__ C,
    int M, int K, int Nc) {
  const int lane = threadIdx.x & 63;
  const int w = threadIdx.x >> 6;
  const int wr = w / WC, wc = w % WC;
  const int g = lane >> 4;
  const int l16 = lane & 15;
  const int row_base = blockIdx.x * (WR * 64) + wr * 64;

  size_t arow[4];
#pragma unroll
  for (int m = 0; m < 4; ++m) {
    int r = row_base + m * 16 + l16;
    if (r >= M) r = M - 1;
    arow[m] = (size_t)r * (ASPLIT ? 2 * K : K);
  }
  int coln[4];
#pragma unroll
  for (int n = 0; n < 4; ++n) coln[n] = wc * 64 + n * 16 + l16;

  f32x4 acc[4][4] = {};

  for (int k0 = 0; k0 < K; k0 += 32) {
    short8v ah[4], al[4];
    if constexpr (ASPLIT) {
      const ushort* As = (const ushort*)Av;
#pragma unroll
      for (int m = 0; m < 4; ++m) {
        const ushort* p = As + arow[m] + k0 + g * 8;
        ah[m] = *(const short8v*)p;
        al[m] = *(const short8v*)(p + K);
      }
    } else {
      const float* A = (const float*)Av;
      float4 a0[4], a1[4];
#pragma unroll
      for (int m = 0; m < 4; ++m) {
        const float* p = A + arow[m] + k0 + g * 8;
        a0[m] = *(const float4*)p;
        a1[m] = *(const float4*)(p + 4);
      }
#pragma unroll
      for (int m = 0; m < 4; ++m) split8(a0[m], a1[m], ah[m], al[m]);
    }
    short8v bh[4], bl[4];
    const int kc = (k0 >> 3) + g;
#pragma unroll
    for (int n = 0; n < 4; ++n) {
      size_t off = ((size_t)kc * Nc + coln[n]) * 8;
      bh[n] = *(const short8v*)(Bhi + off);
      bl[n] = *(const short8v*)(Blo + off);
    }
#pragma unroll
    for (int m = 0; m < 4; ++m)
#pragma unroll
      for (int n = 0; n < 4; ++n) {
        acc[m][n] = __builtin_amdgcn_mfma_f32_16x16x32_bf16(ah[m], bh[n], acc[m][n], 0, 0, 0);
        acc[m][n] = __builtin_amdgcn_mfma_f32_16x16x32_bf16(al[m], bh[n], acc[m][n], 0, 0, 0);
        acc[m][n] = __builtin_amdgcn_mfma_f32_16x16x32_bf16(ah[m], bl[n], acc[m][n], 0, 0, 0);
      }
  }

#pragma unroll
  for (int m = 0; m < 4; ++m)
#pragma unroll
    for (int i = 0; i < 4; ++i) {
      int r = row_base + m * 16 + g * 4 + i;
      if (r < M) {
#pragma unroll
        for (int n = 0; n < 4; ++n) {
          int c = coln[n];
          size_t o;
          if (MODE == 0) o = (size_t)r * Nc + c;
          else o = (r < NND) ? ((size_t)r * 128 + c)
                             : ((size_t)(r - NND) * 128 + 64 + c);
          C[o] = acc[m][n][i];
        }
      }
    }
}

// ---------------- layer-1 aggregation, both norms ----------------
// one wave per node; lanes 0-31 even edges, 32-63 odd edges; float4/lane.
// outputs relu(agg+b1) as split-bf16 rows [hi128|lo128] (hg row wid, hp row NND+wid)

__global__ __launch_bounds__(256) void k_agg1(
    const float* __restrict__ hlin, const int* __restrict__ row_ptr,
    const int4* __restrict__ csr,
    const float* __restrict__ dinv_g, const float* __restrict__ dinv_p,
    const float* __restrict__ b1, ushort* __restrict__ hhs) {
  int wid = (blockIdx.x * blockDim.x + threadIdx.x) >> 6;
  int lane = threadIdx.x & 63;
  if (wid >= NND) return;
  const int half = lane >> 5;
  const int l5 = lane & 31;
  float sg = dinv_g[wid]; sg *= sg;       // self-loop norm = dinv^2
  float sp = dinv_p[wid]; sp *= sp;

  float agx = 0.f, agy = 0.f, agz = 0.f, agw = 0.f;
  float apx = 0.f, apy = 0.f, apz = 0.f, apw = 0.f;
  if (half == 0) {
    float4 v = *(const float4*)(hlin + (size_t)wid * HID + 4 * l5);
    agx = v.x * sg; agy = v.y * sg; agz = v.z * sg; agw = v.w * sg;
    apx = v.x * sp; apy = v.y * sp; apz = v.z * sp; apw = v.w * sp;
  }

  int e0 = row_ptr[wid], e1 = row_ptr[wid + 1];
  int k = e0 + half;
  if (k < e1) {
    int4 rec = csr[k];
    while (true) {
      int kn = k + 2;
      int4 nrec = csr[kn < e1 ? kn : k];        // clamped prefetch
      float wg = __int_as_float(rec.y);
      float wp = __int_as_float(rec.z);
      float4 u = *(const float4*)(hlin + (size_t)rec.x * HID + 4 * l5);
      agx = fmaf(u.x, wg, agx); agy = fmaf(u.y, wg, agy);
      agz = fmaf(u.z, wg, agz); agw = fmaf(u.w, wg, agw);
      apx = fmaf(u.x, wp, apx); apy = fmaf(u.y, wp, apy);
      apz = fmaf(u.z, wp, apz); apw = fmaf(u.w, wp, apw);
      if (kn >= e1) break;
      k = kn; rec = nrec;
    }
  }

  agx += __shfl_xor(agx, 32); agy += __shfl_xor(agy, 32);
  agz += __shfl_xor(agz, 32); agw += __shfl_xor(agw, 32);
  apx += __shfl_xor(apx, 32); apy += __shfl_xor(apy, 32);
  apz += __shfl_xor(apz, 32); apw += __shfl_xor(apw, 32);

  float4 bb = *(const float4*)(b1 + 4 * l5);
  float r0, r1, r2, r3;
  if (half == 0) { r0 = agx + bb.x; r1 = agy + bb.y; r2 = agz + bb.z; r3 = agw + bb.w; }
  else           { r0 = apx + bb.x; r1 = apy + bb.y; r2 = apz + bb.z; r3 = apw + bb.w; }
  r0 = fmaxf(r0, 0.f); r1 = fmaxf(r1, 0.f); r2 = fmaxf(r2, 0.f); r3 = fmaxf(r3, 0.f);

  ushort4 hv, lv;
  split1(r0, hv.x, lv.x); split1(r1, hv.y, lv.y);
  split1(r2, hv.z, lv.z); split1(r3, hv.w, lv.w);
  size_t rowbase = (size_t)(half ? NND + wid : wid) * (2 * HID);
  *(ushort4*)(hhs + rowbase + 4 * l5) = hv;           // hi block [0,128)
  *(ushort4*)(hhs + rowbase + HID + 4 * l5) = lv;     // lo block [128,256)
}

// ---------------- layer-2 aggregation + attention softmax -> emb --------------
// h2 node-interleaved: h2[node][0:64]=g, [64:128]=p.  One wave per node.
// lane = (edge parity ep)<<5 | (branch q)<<4 | t;  float4 covers feats 4t..4t+3.

__global__ __launch_bounds__(256) void k_agg2(
    const float* __restrict__ h2, const int* __restrict__ row_ptr,
    const int4* __restrict__ csr,
    const float* __restrict__ dinv_g, const float* __restrict__ dinv_p,
    const float* __restrict__ b2, const float* __restrict__ att_w,
    const float* __restrict__ att_b, float* __restrict__ out_emb) {
  int wid = (blockIdx.x * blockDim.x + threadIdx.x) >> 6;
  int lane = threadIdx.x & 63;
  if (wid >= NND) return;
  const int ep = lane >> 5;
  const int q  = (lane >> 4) & 1;
  const int t  = lane & 15;
  float sg = dinv_g[wid]; sg *= sg;
  float sp = dinv_p[wid]; sp *= sp;
  const float sw = q ? sp : sg;

  float ax = 0.f, ay = 0.f, az = 0.f, azw = 0.f;
  if (ep == 0) {
    float4 v = *(const float4*)(h2 + (size_t)wid * 128 + q * 64 + 4 * t);
    ax = v.x * sw; ay = v.y * sw; az = v.z * sw; azw = v.w * sw;
  }

  int e0 = row_ptr[wid], e1 = row_ptr[wid + 1];
  int k = e0 + ep;
  if (k < e1) {
    int4 rec = csr[k];
    while (true) {
      int kn = k + 2;
      int4 nrec = csr[kn < e1 ? kn : k];
      float w = __int_as_float(q ? rec.z : rec.y);
      float4 u = *(const float4*)(h2 + (size_t)rec.x * 128 + q * 64 + 4 * t);
      ax = fmaf(u.x, w, ax); ay = fmaf(u.y, w, ay);
      az = fmaf(u.z, w, az); azw = fmaf(u.w, w, azw);
      if (kn >= e1) break;
      k = kn; rec = nrec;
    }
  }

  ax += __shfl_xor(ax, 32); ay += __shfl_xor(ay, 32);
  az += __shfl_xor(az, 32); azw += __shfl_xor(azw, 32);

  float4 bb = *(const float4*)(b2 + 4 * t);
  float vx = ax + bb.x, vy = ay + bb.y, vz = az + bb.z, vw = azw + bb.w;

  float4 aw4 = *(const float4*)(att_w + 4 * t);
  float part = vx * aw4.x + vy * aw4.y + vz * aw4.z + vw * aw4.w;
  part += __shfl_xor(part, 8);
  part += __shfl_xor(part, 4);
  part += __shfl_xor(part, 2);
  part += __shfl_xor(part, 1);
  float other = __shfl_xor(part, 16);
  float ab = att_b[0];
  float lg = (q ? other : part) + ab;
  float lp = (q ? part : other) + ab;
  float mx = fmaxf(lg, lp);
  float egv = expf(lg - mx), epv = expf(lp - mx);
  float wsm = egv / (egv + epv);        // weight of g branch

  float ox = __shfl_xor(vx, 16);
  float oy = __shfl_xor(vy, 16);
  float oz = __shfl_xor(vz, 16);
  float ow = __shfl_xor(vw, 16);
  if (lane < 16) {                       // val = gv, other = pv
    float4 o;
    o.x = wsm * vx + (1.f - wsm) * ox;
    o.y = wsm * vy + (1.f - wsm) * oy;
    o.z = wsm * vz + (1.f - wsm) * oz;
    o.w = wsm * vw + (1.f - wsm) * ow;
    *(float4*)(out_emb + (size_t)wid * 64 + 4 * t) = o;
  }
}

// ---------------- class + domain heads --------------

__global__ __launch_bounds__(128) void k_head(
    const float* __restrict__ emb,
    const float* __restrict__ cls_w, const float* __restrict__ cls_b,
    const float* __restrict__ dw1, const float* __restrict__ db1,
    const float* __restrict__ dw2, const float* __restrict__ db2,
    float* __restrict__ out_cls, float* __restrict__ out_dom) {
  __shared__ float se[128 * 65];
  const int t = threadIdx.x;
  const int base = blockIdx.x * 128;
  for (int c = 0; c < 64; ++c) {
    int idx = c * 128 + t;
    int nl = idx >> 6, k = idx & 63;
    size_t g = (size_t)base * ENC + idx;
    float v = (g < (size_t)NND * ENC) ? emb[g] : 0.f;
    se[nl * 65 + k] = v;
  }
  __syncthreads();

  int node = base + t;
  float c[NCLS], hd[DOM];
#pragma unroll
  for (int j = 0; j < NCLS; ++j) c[j] = cls_b[j];
#pragma unroll
  for (int j = 0; j < DOM; ++j) hd[j] = db1[j];

  for (int k = 0; k < ENC; ++k) {
    float ev = se[t * 65 + k];
#pragma unroll
    for (int j = 0; j < NCLS; ++j) c[j] += ev * cls_w[k * NCLS + j];
#pragma unroll
    for (int j = 0; j < DOM; ++j) hd[j] += ev * dw1[k * DOM + j];
  }
  float d0 = db2[0], d1 = db2[1];
#pragma unroll
  for (int j = 0; j < DOM; ++j) {
    float hv = fmaxf(hd[j], 0.f);
    d0 += hv * dw2[j * 2];
    d1 += hv * dw2[j * 2 + 1];
  }
  if (node < NND) {
#pragma unroll
    for (int j = 0; j < NCLS; ++j) out_cls[(size_t)node * NCLS + j] = c[j];
    out_dom[(size_t)node * 2]     = d0;
    out_dom[(size_t)node * 2 + 1] = d1;
  }
}

// ---------------- host ----------------

extern "C" void kernel_launch(void* const* d_in, const int* in_sizes, int n_in,
                              void* d_out, int out_size, void* d_ws, size_t ws_size,
                              hipStream_t stream) {
  const float* x     = (const float*)d_in[0];
  const int*   ei    = (const int*)d_in[1];
  const float* ppmi  = (const float*)d_in[2];
  const float* W1    = (const float*)d_in[4];
  const float* b1    = (const float*)d_in[5];
  const float* W2    = (const float*)d_in[6];
  const float* b2    = (const float*)d_in[7];
  const float* att_w = (const float*)d_in[8];
  const float* att_b = (const float*)d_in[9];
  const float* cls_w = (const float*)d_in[10];
  const float* cls_b = (const float*)d_in[11];
  const float* dw1   = (const float*)d_in[12];
  const float* db1   = (const float*)d_in[13];
  const float* dw2   = (const float*)d_in[14];
  const float* db2   = (const float*)d_in[15];

  const int* src = ei;
  const int* dst = ei + NED;

  uintptr_t p = (uintptr_t)d_ws;
  auto alloc = [&](size_t bytes) -> void* {
    void* r = (void*)p;
    p += (bytes + 255) & ~(size_t)255;
    return r;
  };
  unsigned long long* packed = (unsigned long long*)alloc((size_t)NND * 8);
  int*    rank    = (int*)   alloc((size_t)NED * 4);
  int*    row_ptr = (int*)   alloc((size_t)(NND + 1) * 4);
  int*    psum    = (int*)   alloc((size_t)NBS * 4);
  float*  dinv_g  = (float*) alloc((size_t)NND * 4);
  float*  dinv_p  = (float*) alloc((size_t)NND * 4);
  int4*   csr     = (int4*)  alloc((size_t)NED * 16);
  ushort* b1hi    = (ushort*)alloc((size_t)FIN * HID * 2);
  ushort* b1lo    = (ushort*)alloc((size_t)FIN * HID * 2);
  ushort* b2hi    = (ushort*)alloc((size_t)HID * ENC * 2);
  ushort* b2lo    = (ushort*)alloc((size_t)HID * ENC * 2);
  float*  h_lin   = (float*) alloc((size_t)NND * HID * 4);       // reused as h2
  ushort* hhs     = (ushort*)alloc((size_t)2 * NND * 2 * HID * 2); // split rows

  float* h2 = h_lin;   // node-interleaved [N][128]: g | p

  float* out_emb = (float*)d_out;
  float* out_cls = (float*)d_out + (size_t)NND * ENC;
  float* out_dom = (float*)d_out + (size_t)NND * (ENC + NCLS);

  // ---- graph preprocessing ----
  hipMemsetAsync(packed, 0, (size_t)NND * 8, stream);

  k_deg_rank<<<NED / 256, 256, 0, stream>>>(dst, ppmi, packed, rank);
  k_dinv<<<(NND + 255) / 256, 256, 0, stream>>>(packed, dinv_g, dinv_p);
  k_scan_a<<<NBS, SCAN_BS, 0, stream>>>(packed, psum);
  k_scan_b<<<1, 512, 0, stream>>>(psum);
  k_scan_c<<<NBS, SCAN_BS, 0, stream>>>(packed, psum, row_ptr);
  k_scatter<<<NED / 256, 256, 0, stream>>>(src, dst, ppmi, row_ptr, rank,
                                           dinv_g, dinv_p, csr);

  // ---- weight preconversion (tiny) ----
  k_bprep<HID><<<(FIN * HID + 255) / 256, 256, 0, stream>>>(W1, b1hi, b1lo, FIN);
  k_bprep<ENC><<<(HID * ENC + 255) / 256, 256, 0, stream>>>(W2, b2hi, b2lo, HID);

  // ---- encoder ----
  // h_lin = x @ W1   (M=100000, K=512, Nc=128), LDS-staged double-buffered
  gemm1_lds<<<(NND + 127) / 128, 256, 0, stream>>>(x, b1hi, b1lo, h_lin);
  k_agg1<<<(NND * 64) / 256, 256, 0, stream>>>(h_lin, row_ptr, csr,
                                               dinv_g, dinv_p, b1, hhs);
  // h2 = [hg;hp] @ W2 (M=2N, K=128, Nc=64), 4x1 waves, pre-split A,
  // node-interleaved output
  gemm_split<4, 1, 1, 1><<<(2 * NND + 255) / 256, 256, 0, stream>>>(
      hhs, b2hi, b2lo, h2, 2 * NND, HID, ENC);
  k_agg2<<<(NND * 64) / 256, 256, 0, stream>>>(h2, row_ptr, csr,
                                               dinv_g, dinv_p, b2, att_w, att_b, out_emb);

  // ---- heads ----
  k_head<<<(NND + 127) / 128, 128, 0, stream>>>(out_emb, cls_w, cls_b, dw1, db1,
                                                dw2, db2, out_cls, out_dom);
}

// Round 7
// 474.719 us; speedup vs baseline: 2.0083x; 1.2270x over previous
//
#include <hip/hip_runtime.h>
#include <math.h>
#include <stdint.h>

#define NND  100000   // nodes
#define NED  1600000  // edges (without self loops)
#define FIN  512
#define HID  128
#define ENC  64
#define NCLS 10
#define DOM  40

#define SCAN_BS 256
#define NBS ((NND + SCAN_BS - 1) / SCAN_BS)   // 391

typedef __attribute__((ext_vector_type(8))) short short8v;
typedef __attribute__((ext_vector_type(8))) unsigned short ushort8v;
typedef __attribute__((ext_vector_type(4))) float f32x4;
typedef __attribute__((ext_vector_type(4))) unsigned int uint4v;

// ---------------- degree + rank: ONE packed 64-bit atomic per edge ----------

__global__ void k_deg_rank(const int* __restrict__ dst, const float* __restrict__ ppmi,
                           unsigned long long* __restrict__ packed,
                           int* __restrict__ rank) {
  int e = blockIdx.x * blockDim.x + threadIdx.x;
  if (e >= NED) return;
  int d = dst[e];
  unsigned int fx = (unsigned int)(ppmi[e] * 1073741824.0f + 0.5f);  // 2^30 scale
  unsigned long long v = (1ull << 40) | (unsigned long long)fx;
  unsigned long long old = atomicAdd(&packed[d], v);
  rank[e] = (int)(old >> 40);
}

__global__ void k_dinv(const unsigned long long* __restrict__ packed,
                       float* __restrict__ dinv_g, float* __restrict__ dinv_p) {
  int i = blockIdx.x * blockDim.x + threadIdx.x;
  if (i >= NND) return;
  unsigned long long pk = packed[i];
  float cnt = (float)(unsigned int)(pk >> 40);
  float dp  = (float)(pk & 0xFFFFFFFFFFull) * (1.0f / 1073741824.0f);
  dinv_g[i] = 1.0f / sqrtf(cnt + 1.0f);
  dinv_p[i] = 1.0f / sqrtf(dp + 1.0f);
}

// ---------------- 3-kernel exclusive scan (row_ptr) over packed counts -------

__global__ void k_scan_a(const unsigned long long* __restrict__ packed,
                         int* __restrict__ psum) {
  __shared__ int s[SCAN_BS];
  int t = threadIdx.x, i = blockIdx.x * SCAN_BS + t;
  s[t] = (i < NND) ? (int)(packed[i] >> 40) : 0;
  __syncthreads();
  for (int o = SCAN_BS / 2; o; o >>= 1) {
    if (t < o) s[t] += s[t + o];
    __syncthreads();
  }
  if (t == 0) psum[blockIdx.x] = s[0];
}

__global__ void k_scan_b(int* __restrict__ psum) {
  __shared__ int s[512];
  int t = threadIdx.x;
  int v = (t < NBS) ? psum[t] : 0;
  s[t] = v;
  __syncthreads();
  for (int o = 1; o < 512; o <<= 1) {
    int add = (t >= o) ? s[t - o] : 0;
    __syncthreads();
    s[t] += add;
    __syncthreads();
  }
  if (t < NBS) psum[t] = s[t] - v;   // exclusive
}

__global__ void k_scan_c(const unsigned long long* __restrict__ packed,
                         const int* __restrict__ psum, int* __restrict__ row_ptr) {
  __shared__ int s[SCAN_BS];
  int t = threadIdx.x, i = blockIdx.x * SCAN_BS + t;
  int v = (i < NND) ? (int)(packed[i] >> 40) : 0;
  s[t] = v;
  __syncthreads();
  for (int o = 1; o < SCAN_BS; o <<= 1) {
    int add = (t >= o) ? s[t - o] : 0;
    __syncthreads();
    s[t] += add;
    __syncthreads();
  }
  if (i < NND) row_ptr[i] = psum[blockIdx.x] + s[t] - v;
  if (i == NND - 1) row_ptr[NND] = psum[blockIdx.x] + s[t];
}

// ---------------- CSR scatter: atomic-free (pos = row_ptr[d] + rank[e]) ------

__global__ void k_scatter(const int* __restrict__ src, const int* __restrict__ dst,
                          const float* __restrict__ ppmi,
                          const int* __restrict__ row_ptr, const int* __restrict__ rank,
                          const float* __restrict__ dinv_g, const float* __restrict__ dinv_p,
                          int4* __restrict__ csr) {
  int e = blockIdx.x * blockDim.x + threadIdx.x;
  if (e >= NED) return;
  int s = src[e], d = dst[e];
  int pos = row_ptr[d] + rank[e];
  int4 rec;
  rec.x = s;
  rec.y = __float_as_int(dinv_g[s] * dinv_g[d]);
  rec.z = __float_as_int(dinv_p[s] * ppmi[e] * dinv_p[d]);
  rec.w = 0;
  csr[pos] = rec;
}

// ---------------- B preconversion to split-bf16 fragment layout --------------

template<int NC>
__global__ void k_bprep(const float* __restrict__ B, ushort* __restrict__ bhi,
                        ushort* __restrict__ blo, int K) {
  int id = blockIdx.x * 256 + threadIdx.x;
  if (id >= K * NC) return;
  int k = id / NC, c = id % NC;
  float x = B[id];
  unsigned int u = __float_as_uint(x);
  ushort h = (ushort)(u >> 16);
  float lo = x - __uint_as_float(u & 0xffff0000u);
  ushort l = (ushort)(__float_as_uint(lo) >> 16);
  size_t o = ((size_t)(k >> 3) * NC + c) * 8 + (k & 7);
  bhi[o] = h;
  blo[o] = l;
}

// ---------------- helpers ----------------

__device__ inline void split8(const float4 a, const float4 b,
                              short8v& hi, short8v& lo) {
  float f[8] = {a.x, a.y, a.z, a.w, b.x, b.y, b.z, b.w};
  uint4v H, L;
#pragma unroll
  for (int i = 0; i < 4; ++i) {
    unsigned int u0 = __float_as_uint(f[2 * i]);
    unsigned int u1 = __float_as_uint(f[2 * i + 1]);
    H[i] = (u0 >> 16) | (u1 & 0xffff0000u);
    float l0 = f[2 * i]     - __uint_as_float(u0 & 0xffff0000u);
    float l1 = f[2 * i + 1] - __uint_as_float(u1 & 0xffff0000u);
    L[i] = (__float_as_uint(l0) >> 16) | (__float_as_uint(l1) & 0xffff0000u);
  }
  hi = __builtin_bit_cast(short8v, H);
  lo = __builtin_bit_cast(short8v, L);
}

__device__ inline void split1(float x, ushort& h, ushort& l) {
  unsigned int u = __float_as_uint(x);
  h = (ushort)(u >> 16);
  float r = x - __uint_as_float(u & 0xffff0000u);
  l = (ushort)(__float_as_uint(r) >> 16);
}

__device__ inline ushort f2bf_rne(float x) {
  unsigned int u = __float_as_uint(x);
  unsigned int r = u + 0x7fffu + ((u >> 16) & 1u);
  return (ushort)(r >> 16);
}

__device__ inline float bf2f(unsigned short v) {
  return __uint_as_float((unsigned int)v << 16);
}

// ---------------- GEMM1: h_linb(bf16) = x @ W1, LDS-staged split-bf16 MFMA ---

__device__ inline void gload_lds16(const float* gp, float* lp) {
  __builtin_amdgcn_global_load_lds(
      (const __attribute__((address_space(1))) void*)gp,
      (__attribute__((address_space(3))) void*)lp, 16, 0, 0);
}

__global__ __launch_bounds__(256, 2) void gemm1_lds(
    const float* __restrict__ A, const ushort* __restrict__ Bhi,
    const ushort* __restrict__ Blo, ushort* __restrict__ C) {
  __shared__ float At[2][128 * 32];
  const int tid = threadIdx.x;
  const int lane = tid & 63;
  const int w = tid >> 6;
  const int wr = w >> 1, wc = w & 1;
  const int g = lane >> 4;
  const int l16 = lane & 15;
  const int row_base = blockIdx.x * 128;

  size_t srow[4]; int scol[4];
  {
    int e = w * 256 + lane * 4;
#pragma unroll
    for (int i = 0; i < 4; ++i) {
      int ee = e + i * 1024;
      int r = ee >> 5;
      int chunk_lds = (ee >> 2) & 7;
      int chunk_g = chunk_lds ^ (r & 7);
      int rr = row_base + r; if (rr >= NND) rr = NND - 1;
      srow[i] = (size_t)rr * FIN;
      scol[i] = chunk_g * 4;
    }
  }

  int coln[4];
#pragma unroll
  for (int n = 0; n < 4; ++n) coln[n] = wc * 64 + n * 16 + l16;
  int arow_l[4];
#pragma unroll
  for (int m = 0; m < 4; ++m) arow_l[m] = wr * 64 + m * 16 + l16;

  f32x4 acc[4][4] = {};

#pragma unroll
  for (int i = 0; i < 4; ++i)
    gload_lds16(A + srow[i] + 0 + scol[i], &At[0][w * 256 + i * 1024]);
  __syncthreads();

  for (int t = 0; t < FIN / 32; ++t) {
    const int cur = t & 1;
    if (t + 1 < FIN / 32) {
      const int k0n = (t + 1) * 32;
#pragma unroll
      for (int i = 0; i < 4; ++i)
        gload_lds16(A + srow[i] + k0n + scol[i], &At[cur ^ 1][w * 256 + i * 1024]);
    }

    short8v ah[4], al[4];
#pragma unroll
    for (int m = 0; m < 4; ++m) {
      int r = arow_l[m];
      int c0 = (((g * 2)     ^ (r & 7)) << 2);
      int c1 = (((g * 2 + 1) ^ (r & 7)) << 2);
      float4 a0 = *(const float4*)&At[cur][r * 32 + c0];
      float4 a1 = *(const float4*)&At[cur][r * 32 + c1];
      split8(a0, a1, ah[m], al[m]);
    }

    short8v bh[4], bl[4];
    const int kc = t * 4 + g;
#pragma unroll
    for (int n = 0; n < 4; ++n) {
      size_t off = ((size_t)kc * HID + coln[n]) * 8;
      bh[n] = *(const short8v*)(Bhi + off);
      bl[n] = *(const short8v*)(Blo + off);
    }

#pragma unroll
    for (int m = 0; m < 4; ++m)
#pragma unroll
      for (int n = 0; n < 4; ++n) {
        acc[m][n] = __builtin_amdgcn_mfma_f32_16x16x32_bf16(ah[m], bh[n], acc[m][n], 0, 0, 0);
        acc[m][n] = __builtin_amdgcn_mfma_f32_16x16x32_bf16(al[m], bh[n], acc[m][n], 0, 0, 0);
        acc[m][n] = __builtin_amdgcn_mfma_f32_16x16x32_bf16(ah[m], bl[n], acc[m][n], 0, 0, 0);
      }

    __syncthreads();
  }

  // C/D layout: col = lane&15, row = (lane>>4)*4 + reg; wave offset wr*64 included
#pragma unroll
  for (int m = 0; m < 4; ++m)
#pragma unroll
    for (int i = 0; i < 4; ++i) {
      int r = row_base + wr * 64 + m * 16 + g * 4 + i;
      if (r < NND) {
#pragma unroll
        for (int n = 0; n < 4; ++n)
          C[(size_t)r * HID + coln[n]] = f2bf_rne(acc[m][n][i]);
      }
    }
}

// ---------------- GEMM2: h2b(bf16) = [hg;hp] @ W2, register-A split-bf16 -----
// A rows: [hi bf16 x K | lo bf16 x K]. Output node-interleaved bf16:
// rows [0,NND) -> h2b[r][c], rows [NND,2NND) -> h2b[r-NND][64+c].

template<int WR>
__global__ __launch_bounds__(256, 2) void gemm2_split(
    const ushort* __restrict__ As, const ushort* __restrict__ Bhi,
    const ushort* __restrict__ Blo, ushort* __restrict__ C,
    int M, int K, int Nc) {
  const int lane = threadIdx.x & 63;
  const int w = threadIdx.x >> 6;
  const int g = lane >> 4;
  const int l16 = lane & 15;
  const int row_base = blockIdx.x * (WR * 64) + w * 64;

  size_t arow[4];
#pragma unroll
  for (int m = 0; m < 4; ++m) {
    int r = row_base + m * 16 + l16;
    if (r >= M) r = M - 1;
    arow[m] = (size_t)r * 2 * K;
  }
  int coln[4];
#pragma unroll
  for (int n = 0; n < 4; ++n) coln[n] = n * 16 + l16;

  f32x4 acc[4][4] = {};

  for (int k0 = 0; k0 < K; k0 += 32) {
    short8v ah[4], al[4];
#pragma unroll
    for (int m = 0; m < 4; ++m) {
      const ushort* p = As + arow[m] + k0 + g * 8;
      ah[m] = *(const short8v*)p;
      al[m] = *(const short8v*)(p + K);
    }
    short8v bh[4], bl[4];
    const int kc = (k0 >> 3) + g;
#pragma unroll
    for (int n = 0; n < 4; ++n) {
      size_t off = ((size_t)kc * Nc + coln[n]) * 8;
      bh[n] = *(const short8v*)(Bhi + off);
      bl[n] = *(const short8v*)(Blo + off);
    }
#pragma unroll
    for (int m = 0; m < 4; ++m)
#pragma unroll
      for (int n = 0; n < 4; ++n) {
        acc[m][n] = __builtin_amdgcn_mfma_f32_16x16x32_bf16(ah[m], bh[n], acc[m][n], 0, 0, 0);
        acc[m][n] = __builtin_amdgcn_mfma_f32_16x16x32_bf16(al[m], bh[n], acc[m][n], 0, 0, 0);
        acc[m][n] = __builtin_amdgcn_mfma_f32_16x16x32_bf16(ah[m], bl[n], acc[m][n], 0, 0, 0);
      }
  }

#pragma unroll
  for (int m = 0; m < 4; ++m)
#pragma unroll
    for (int i = 0; i < 4; ++i) {
      int r = row_base + m * 16 + g * 4 + i;
      if (r < M) {
#pragma unroll
        for (int n = 0; n < 4; ++n) {
          int c = coln[n];
          size_t o = (r < NND) ? ((size_t)r * 128 + c)
                               : ((size_t)(r - NND) * 128 + 64 + c);
          C[o] = f2bf_rne(acc[m][n][i]);
        }
      }
    }
}

// ---------------- layer-1 aggregation: bf16 gathers, 4 edges in flight -------
// one wave/node; 4 groups x 16 lanes; lane covers feats 8t..8t+7 (ushort8=16B).
// outputs relu(agg+b1) as split-bf16 rows [hi128|lo128].

__global__ __launch_bounds__(256) void k_agg1(
    const ushort* __restrict__ hlinb, const int* __restrict__ row_ptr,
    const int4* __restrict__ csr,
    const float* __restrict__ dinv_g, const float* __restrict__ dinv_p,
    const float* __restrict__ b1, ushort* __restrict__ hhs) {
  int wid = (blockIdx.x * blockDim.x + threadIdx.x) >> 6;
  int lane = threadIdx.x & 63;
  if (wid >= NND) return;
  const int gp = lane >> 4;
  const int t  = lane & 15;
  float sg = dinv_g[wid]; sg *= sg;
  float sp = dinv_p[wid]; sp *= sp;

  float ag[8] = {}, ap[8] = {};
  if (gp == 0) {
    ushort8v v = *(const ushort8v*)(hlinb + (size_t)wid * HID + 8 * t);
#pragma unroll
    for (int i = 0; i < 8; ++i) {
      float f = bf2f(v[i]);
      ag[i] = f * sg; ap[i] = f * sp;
    }
  }
  int e0 = row_ptr[wid], e1 = row_ptr[wid + 1];
  int k = e0 + gp;
  if (k < e1) {
    int4 rec = csr[k];
    while (true) {
      int kn = k + 4;
      int4 nrec = csr[kn < e1 ? kn : k];      // clamped prefetch
      float wg = __int_as_float(rec.y);
      float wp = __int_as_float(rec.z);
      ushort8v u = *(const ushort8v*)(hlinb + (size_t)rec.x * HID + 8 * t);
#pragma unroll
      for (int i = 0; i < 8; ++i) {
        float f = bf2f(u[i]);
        ag[i] = fmaf(f, wg, ag[i]);
        ap[i] = fmaf(f, wp, ap[i]);
      }
      if (kn >= e1) break;
      k = kn; rec = nrec;
    }
  }
#pragma unroll
  for (int i = 0; i < 8; ++i) {
    ag[i] += __shfl_xor(ag[i], 32); ap[i] += __shfl_xor(ap[i], 32);
    ag[i] += __shfl_xor(ag[i], 16); ap[i] += __shfl_xor(ap[i], 16);
  }

  float bb[8];
  *(float4*)&bb[0] = *(const float4*)(b1 + 8 * t);
  *(float4*)&bb[4] = *(const float4*)(b1 + 8 * t + 4);
  ushort8v outv;
#pragma unroll
  for (int i = 0; i < 8; ++i) {
    float vg = fmaxf(ag[i] + bb[i], 0.f);
    float vp = fmaxf(ap[i] + bb[i], 0.f);
    ushort gh, gl, ph, pl;
    split1(vg, gh, gl); split1(vp, ph, pl);
    outv[i] = (gp == 0) ? gh : (gp == 1) ? gl : (gp == 2) ? ph : pl;
  }
  size_t rowg = (size_t)wid * (2 * HID);
  size_t rowp = (size_t)(NND + wid) * (2 * HID);
  size_t off = (gp == 0) ? rowg + 8 * t : (gp == 1) ? rowg + HID + 8 * t
             : (gp == 2) ? rowp + 8 * t : rowp + HID + 8 * t;
  *(ushort8v*)(hhs + off) = outv;
}

// ---------------- layer-2 aggregation + attention -> emb ---------------------
// h2b node-interleaved bf16 [node][128]: g|p. 4 groups x 16 lanes; within a
// group: t<8 accumulates g feats 8t.., t>=8 accumulates p feats 8(t-8)..

__global__ __launch_bounds__(256) void k_agg2(
    const ushort* __restrict__ h2b, const int* __restrict__ row_ptr,
    const int4* __restrict__ csr,
    const float* __restrict__ dinv_g, const float* __restrict__ dinv_p,
    const float* __restrict__ b2, const float* __restrict__ att_w,
    const float* __restrict__ att_b, float* __restrict__ out_emb) {
  int wid = (blockIdx.x * blockDim.x + threadIdx.x) >> 6;
  int lane = threadIdx.x & 63;
  if (wid >= NND) return;
  const int gp = lane >> 4;
  const int t  = lane & 15;
  const int br = t >> 3;            // 0 = g branch, 1 = p branch
  const int f0 = (t & 7) * 8;       // feature base within branch
  float sg = dinv_g[wid]; sg *= sg;
  float sp = dinv_p[wid]; sp *= sp;
  const float sw = br ? sp : sg;

  float acc[8] = {};
  if (gp == 0) {
    ushort8v v = *(const ushort8v*)(h2b + (size_t)wid * 128 + 8 * t);
#pragma unroll
    for (int i = 0; i < 8; ++i) acc[i] = bf2f(v[i]) * sw;
  }
  int e0 = row_ptr[wid], e1 = row_ptr[wid + 1];
  int k = e0 + gp;
  if (k < e1) {
    int4 rec = csr[k];
    while (true) {
      int kn = k + 4;
      int4 nrec = csr[kn < e1 ? kn : k];
      float w = __int_as_float(br ? rec.z : rec.y);
      ushort8v u = *(const ushort8v*)(h2b + (size_t)rec.x * 128 + 8 * t);
#pragma unroll
      for (int i = 0; i < 8; ++i) acc[i] = fmaf(bf2f(u[i]), w, acc[i]);
      if (kn >= e1) break;
      k = kn; rec = nrec;
    }
  }
#pragma unroll
  for (int i = 0; i < 8; ++i) {
    acc[i] += __shfl_xor(acc[i], 32);
    acc[i] += __shfl_xor(acc[i], 16);
  }

  float bb[8];
  *(float4*)&bb[0] = *(const float4*)(b2 + f0);
  *(float4*)&bb[4] = *(const float4*)(b2 + f0 + 4);
  float v[8];
#pragma unroll
  for (int i = 0; i < 8; ++i) v[i] = acc[i] + bb[i];

  float aw[8];
  *(float4*)&aw[0] = *(const float4*)(att_w + f0);
  *(float4*)&aw[4] = *(const float4*)(att_w + f0 + 4);
  float part = 0.f;
#pragma unroll
  for (int i = 0; i < 8; ++i) part = fmaf(v[i], aw[i], part);
  part += __shfl_xor(part, 4);
  part += __shfl_xor(part, 2);
  part += __shfl_xor(part, 1);
  float other = __shfl_xor(part, 8);
  float ab = att_b[0];
  float lg = (br ? other : part) + ab;
  float lp = (br ? part : other) + ab;
  float mx = fmaxf(lg, lp);
  float eg = expf(lg - mx), ep2 = expf(lp - mx);
  float wsm = eg / (eg + ep2);          // weight of g branch

  float ov[8];
#pragma unroll
  for (int i = 0; i < 8; ++i) ov[i] = __shfl_xor(v[i], 8);
  if (gp == 0 && br == 0) {
    float4* dst = (float4*)(out_emb + (size_t)wid * 64 + f0);
    float4 o0, o1;
    o0.x = wsm * v[0] + (1.f - wsm) * ov[0];
    o0.y = wsm * v[1] + (1.f - wsm) * ov[1];
    o0.z = wsm * v[2] + (1.f - wsm) * ov[2];
    o0.w = wsm * v[3] + (1.f - wsm) * ov[3];
    o1.x = wsm * v[4] + (1.f - wsm) * ov[4];
    o1.y = wsm * v[5] + (1.f - wsm) * ov[5];
    o1.z = wsm * v[6] + (1.f - wsm) * ov[6];
    o1.w = wsm * v[7] + (1.f - wsm) * ov[7];
    dst[0] = o0;
    dst[1] = o1;
  }
}

// ---------------- class + domain heads --------------

__global__ __launch_bounds__(128) void k_head(
    const float* __restrict__ emb,
    const float* __restrict__ cls_w, const float* __restrict__ cls_b,
    const float* __restrict__ dw1, const float* __restrict__ db1,
    const float* __restrict__ dw2, const float* __restrict__ db2,
    float* __restrict__ out_cls, float* __restrict__ out_dom) {
  __shared__ float se[128 * 65];
  const int t = threadIdx.x;
  const int base = blockIdx.x * 128;
  for (int c = 0; c < 64; ++c) {
    int idx = c * 128 + t;
    int nl = idx >> 6, k = idx & 63;
    size_t g = (size_t)base * ENC + idx;
    float v = (g < (size_t)NND * ENC) ? emb[g] : 0.f;
    se[nl * 65 + k] = v;
  }
  __syncthreads();

  int node = base + t;
  float c[NCLS], hd[DOM];
#pragma unroll
  for (int j = 0; j < NCLS; ++j) c[j] = cls_b[j];
#pragma unroll
  for (int j = 0; j < DOM; ++j) hd[j] = db1[j];

  for (int k = 0; k < ENC; ++k) {
    float ev = se[t * 65 + k];
#pragma unroll
    for (int j = 0; j < NCLS; ++j) c[j] += ev * cls_w[k * NCLS + j];
#pragma unroll
    for (int j = 0; j < DOM; ++j) hd[j] += ev * dw1[k * DOM + j];
  }
  float d0 = db2[0], d1 = db2[1];
#pragma unroll
  for (int j = 0; j < DOM; ++j) {
    float hv = fmaxf(hd[j], 0.f);
    d0 += hv * dw2[j * 2];
    d1 += hv * dw2[j * 2 + 1];
  }
  if (node < NND) {
#pragma unroll
    for (int j = 0; j < NCLS; ++j) out_cls[(size_t)node * NCLS + j] = c[j];
    out_dom[(size_t)node * 2]     = d0;
    out_dom[(size_t)node * 2 + 1] = d1;
  }
}

// ---------------- host ----------------

extern "C" void kernel_launch(void* const* d_in, const int* in_sizes, int n_in,
                              void* d_out, int out_size, void* d_ws, size_t ws_size,
                              hipStream_t stream) {
  const float* x     = (const float*)d_in[0];
  const int*   ei    = (const int*)d_in[1];
  const float* ppmi  = (const float*)d_in[2];
  const float* W1    = (const float*)d_in[4];
  const float* b1    = (const float*)d_in[5];
  const float* W2    = (const float*)d_in[6];
  const float* b2    = (const float*)d_in[7];
  const float* att_w = (const float*)d_in[8];
  const float* att_b = (const float*)d_in[9];
  const float* cls_w = (const float*)d_in[10];
  const float* cls_b = (const float*)d_in[11];
  const float* dw1   = (const float*)d_in[12];
  const float* db1   = (const float*)d_in[13];
  const float* dw2   = (const float*)d_in[14];
  const float* db2   = (const float*)d_in[15];

  const int* src = ei;
  const int* dst = ei + NED;

  uintptr_t p = (uintptr_t)d_ws;
  auto alloc = [&](size_t bytes) -> void* {
    void* r = (void*)p;
    p += (bytes + 255) & ~(size_t)255;
    return r;
  };
  unsigned long long* packed = (unsigned long long*)alloc((size_t)NND * 8);
  int*    rank    = (int*)   alloc((size_t)NED * 4);
  int*    row_ptr = (int*)   alloc((size_t)(NND + 1) * 4);
  int*    psum    = (int*)   alloc((size_t)NBS * 4);
  float*  dinv_g  = (float*) alloc((size_t)NND * 4);
  float*  dinv_p  = (float*) alloc((size_t)NND * 4);
  int4*   csr     = (int4*)  alloc((size_t)NED * 16);
  ushort* b1hi    = (ushort*)alloc((size_t)FIN * HID * 2);
  ushort* b1lo    = (ushort*)alloc((size_t)FIN * HID * 2);
  ushort* b2hi    = (ushort*)alloc((size_t)HID * ENC * 2);
  ushort* b2lo    = (ushort*)alloc((size_t)HID * ENC * 2);
  ushort* h2b     = (ushort*)alloc((size_t)NND * HID * 2);        // bf16 h2 pair
  ushort* hhs     = (ushort*)alloc((size_t)2 * NND * 2 * HID * 2); // split rows

  float* out_emb = (float*)d_out;
  float* out_cls = (float*)d_out + (size_t)NND * ENC;
  float* out_dom = (float*)d_out + (size_t)NND * (ENC + NCLS);

  // bf16 h_lin lives in the d_out emb region (NND*128*2B == NND*64*4B exactly);
  // dead before agg2 overwrites the region with emb.
  ushort* h_linb = (ushort*)d_out;

  // ---- graph preprocessing ----
  hipMemsetAsync(packed, 0, (size_t)NND * 8, stream);

  k_deg_rank<<<NED / 256, 256, 0, stream>>>(dst, ppmi, packed, rank);
  k_dinv<<<(NND + 255) / 256, 256, 0, stream>>>(packed, dinv_g, dinv_p);
  k_scan_a<<<NBS, SCAN_BS, 0, stream>>>(packed, psum);
  k_scan_b<<<1, 512, 0, stream>>>(psum);
  k_scan_c<<<NBS, SCAN_BS, 0, stream>>>(packed, psum, row_ptr);
  k_scatter<<<NED / 256, 256, 0, stream>>>(src, dst, ppmi, row_ptr, rank,
                                           dinv_g, dinv_p, csr);

  // ---- weight preconversion (tiny) ----
  k_bprep<HID><<<(FIN * HID + 255) / 256, 256, 0, stream>>>(W1, b1hi, b1lo, FIN);
  k_bprep<ENC><<<(HID * ENC + 255) / 256, 256, 0, stream>>>(W2, b2hi, b2lo, HID);

  // ---- encoder ----
  gemm1_lds<<<(NND + 127) / 128, 256, 0, stream>>>(x, b1hi, b1lo, h_linb);
  k_agg1<<<(NND * 64) / 256, 256, 0, stream>>>(h_linb, row_ptr, csr,
                                               dinv_g, dinv_p, b1, hhs);
  gemm2_split<4><<<(2 * NND + 255) / 256, 256, 0, stream>>>(
      hhs, b2hi, b2lo, h2b, 2 * NND, HID, ENC);
  k_agg2<<<(NND * 64) / 256, 256, 0, stream>>>(h2b, row_ptr, csr,
                                               dinv_g, dinv_p, b2, att_w, att_b, out_emb);

  // ---- heads ----
  k_head<<<(NND + 127) / 128, 128, 0, stream>>>(out_emb, cls_w, cls_b, dw1, db1,
                                                dw2, db2, out_cls, out_dom);
}

// Round 8
// 455.928 us; speedup vs baseline: 2.0911x; 1.0412x over previous
//
#include <hip/hip_runtime.h>
#include <math.h>
#include <stdint.h>

#define NND  100000   // nodes
#define NED  1600000  // edges (without self loops)
#define FIN  512
#define HID  128
#define ENC  64
#define NCLS 10
#define DOM  40

#define SCAN_BS 256
#define NBS ((NND + SCAN_BS - 1) / SCAN_BS)   // 391

typedef __attribute__((ext_vector_type(8))) short short8v;
typedef __attribute__((ext_vector_type(8))) unsigned short ushort8v;
typedef __attribute__((ext_vector_type(4))) float f32x4;
typedef __attribute__((ext_vector_type(4))) unsigned int uint4v;

// ---------------- degree + rank: ONE packed 64-bit atomic per edge ----------

__global__ void k_deg_rank(const int* __restrict__ dst, const float* __restrict__ ppmi,
                           unsigned long long* __restrict__ packed,
                           int* __restrict__ rank) {
  int e = blockIdx.x * blockDim.x + threadIdx.x;
  if (e >= NED) return;
  int d = dst[e];
  unsigned int fx = (unsigned int)(ppmi[e] * 1073741824.0f + 0.5f);  // 2^30 scale
  unsigned long long v = (1ull << 40) | (unsigned long long)fx;
  unsigned long long old = atomicAdd(&packed[d], v);
  rank[e] = (int)(old >> 40);
}

__global__ void k_dinv(const unsigned long long* __restrict__ packed,
                       float* __restrict__ dinv_g, float* __restrict__ dinv_p) {
  int i = blockIdx.x * blockDim.x + threadIdx.x;
  if (i >= NND) return;
  unsigned long long pk = packed[i];
  float cnt = (float)(unsigned int)(pk >> 40);
  float dp  = (float)(pk & 0xFFFFFFFFFFull) * (1.0f / 1073741824.0f);
  dinv_g[i] = 1.0f / sqrtf(cnt + 1.0f);
  dinv_p[i] = 1.0f / sqrtf(dp + 1.0f);
}

// ---------------- 3-kernel exclusive scan (row_ptr) over packed counts -------

__global__ void k_scan_a(const unsigned long long* __restrict__ packed,
                         int* __restrict__ psum) {
  __shared__ int s[SCAN_BS];
  int t = threadIdx.x, i = blockIdx.x * SCAN_BS + t;
  s[t] = (i < NND) ? (int)(packed[i] >> 40) : 0;
  __syncthreads();
  for (int o = SCAN_BS / 2; o; o >>= 1) {
    if (t < o) s[t] += s[t + o];
    __syncthreads();
  }
  if (t == 0) psum[blockIdx.x] = s[0];
}

__global__ void k_scan_b(int* __restrict__ psum) {
  __shared__ int s[512];
  int t = threadIdx.x;
  int v = (t < NBS) ? psum[t] : 0;
  s[t] = v;
  __syncthreads();
  for (int o = 1; o < 512; o <<= 1) {
    int add = (t >= o) ? s[t - o] : 0;
    __syncthreads();
    s[t] += add;
    __syncthreads();
  }
  if (t < NBS) psum[t] = s[t] - v;   // exclusive
}

__global__ void k_scan_c(const unsigned long long* __restrict__ packed,
                         const int* __restrict__ psum, int* __restrict__ row_ptr) {
  __shared__ int s[SCAN_BS];
  int t = threadIdx.x, i = blockIdx.x * SCAN_BS + t;
  int v = (i < NND) ? (int)(packed[i] >> 40) : 0;
  s[t] = v;
  __syncthreads();
  for (int o = 1; o < SCAN_BS; o <<= 1) {
    int add = (t >= o) ? s[t - o] : 0;
    __syncthreads();
    s[t] += add;
    __syncthreads();
  }
  if (i < NND) row_ptr[i] = psum[blockIdx.x] + s[t] - v;
  if (i == NND - 1) row_ptr[NND] = psum[blockIdx.x] + s[t];
}

// ---------------- CSR scatter: atomic-free (pos = row_ptr[d] + rank[e]) ------

__global__ void k_scatter(const int* __restrict__ src, const int* __restrict__ dst,
                          const float* __restrict__ ppmi,
                          const int* __restrict__ row_ptr, const int* __restrict__ rank,
                          const float* __restrict__ dinv_g, const float* __restrict__ dinv_p,
                          int4* __restrict__ csr) {
  int e = blockIdx.x * blockDim.x + threadIdx.x;
  if (e >= NED) return;
  int s = src[e], d = dst[e];
  int pos = row_ptr[d] + rank[e];
  int4 rec;
  rec.x = s;
  rec.y = __float_as_int(dinv_g[s] * dinv_g[d]);
  rec.z = __float_as_int(dinv_p[s] * ppmi[e] * dinv_p[d]);
  rec.w = 0;
  csr[pos] = rec;
}

// ---------------- B preconversion to split-bf16 fragment layout --------------

template<int NC>
__global__ void k_bprep(const float* __restrict__ B, ushort* __restrict__ bhi,
                        ushort* __restrict__ blo, int K) {
  int id = blockIdx.x * 256 + threadIdx.x;
  if (id >= K * NC) return;
  int k = id / NC, c = id % NC;
  float x = B[id];
  unsigned int u = __float_as_uint(x);
  ushort h = (ushort)(u >> 16);
  float lo = x - __uint_as_float(u & 0xffff0000u);
  ushort l = (ushort)(__float_as_uint(lo) >> 16);
  size_t o = ((size_t)(k >> 3) * NC + c) * 8 + (k & 7);
  bhi[o] = h;
  blo[o] = l;
}

// ---------------- helpers ----------------

__device__ inline void split8(const float4 a, const float4 b,
                              short8v& hi, short8v& lo) {
  float f[8] = {a.x, a.y, a.z, a.w, b.x, b.y, b.z, b.w};
  uint4v H, L;
#pragma unroll
  for (int i = 0; i < 4; ++i) {
    unsigned int u0 = __float_as_uint(f[2 * i]);
    unsigned int u1 = __float_as_uint(f[2 * i + 1]);
    H[i] = (u0 >> 16) | (u1 & 0xffff0000u);
    float l0 = f[2 * i]     - __uint_as_float(u0 & 0xffff0000u);
    float l1 = f[2 * i + 1] - __uint_as_float(u1 & 0xffff0000u);
    L[i] = (__float_as_uint(l0) >> 16) | (__float_as_uint(l1) & 0xffff0000u);
  }
  hi = __builtin_bit_cast(short8v, H);
  lo = __builtin_bit_cast(short8v, L);
}

__device__ inline ushort f2bf_rne(float x) {
  unsigned int u = __float_as_uint(x);
  unsigned int r = u + 0x7fffu + ((u >> 16) & 1u);
  return (ushort)(r >> 16);
}

__device__ inline float bf2f(unsigned short v) {
  return __uint_as_float((unsigned int)v << 16);
}

// ---------------- GEMM1: h_linb(bf16) = x @ W1, LDS-staged split-bf16 MFMA ---

__device__ inline void gload_lds16(const float* gp, float* lp) {
  __builtin_amdgcn_global_load_lds(
      (const __attribute__((address_space(1))) void*)gp,
      (__attribute__((address_space(3))) void*)lp, 16, 0, 0);
}

__global__ __launch_bounds__(256, 3) void gemm1_lds(
    const float* __restrict__ A, const ushort* __restrict__ Bhi,
    const ushort* __restrict__ Blo, ushort* __restrict__ C) {
  __shared__ float At[2][128 * 32];
  const int tid = threadIdx.x;
  const int lane = tid & 63;
  const int w = tid >> 6;
  const int wr = w >> 1, wc = w & 1;
  const int g = lane >> 4;
  const int l16 = lane & 15;
  const int row_base = blockIdx.x * 128;

  size_t srow[4]; int scol[4];
  {
    int e = w * 256 + lane * 4;
#pragma unroll
    for (int i = 0; i < 4; ++i) {
      int ee = e + i * 1024;
      int r = ee >> 5;
      int chunk_lds = (ee >> 2) & 7;
      int chunk_g = chunk_lds ^ (r & 7);
      int rr = row_base + r; if (rr >= NND) rr = NND - 1;
      srow[i] = (size_t)rr * FIN;
      scol[i] = chunk_g * 4;
    }
  }

  int coln[4];
#pragma unroll
  for (int n = 0; n < 4; ++n) coln[n] = wc * 64 + n * 16 + l16;
  int arow_l[4];
#pragma unroll
  for (int m = 0; m < 4; ++m) arow_l[m] = wr * 64 + m * 16 + l16;

  f32x4 acc[4][4] = {};

#pragma unroll
  for (int i = 0; i < 4; ++i)
    gload_lds16(A + srow[i] + 0 + scol[i], &At[0][w * 256 + i * 1024]);
  __syncthreads();

  for (int t = 0; t < FIN / 32; ++t) {
    const int cur = t & 1;
    if (t + 1 < FIN / 32) {
      const int k0n = (t + 1) * 32;
#pragma unroll
      for (int i = 0; i < 4; ++i)
        gload_lds16(A + srow[i] + k0n + scol[i], &At[cur ^ 1][w * 256 + i * 1024]);
    }

    short8v ah[4], al[4];
#pragma unroll
    for (int m = 0; m < 4; ++m) {
      int r = arow_l[m];
      int c0 = (((g * 2)     ^ (r & 7)) << 2);
      int c1 = (((g * 2 + 1) ^ (r & 7)) << 2);
      float4 a0 = *(const float4*)&At[cur][r * 32 + c0];
      float4 a1 = *(const float4*)&At[cur][r * 32 + c1];
      split8(a0, a1, ah[m], al[m]);
    }

    short8v bh[4], bl[4];
    const int kc = t * 4 + g;
#pragma unroll
    for (int n = 0; n < 4; ++n) {
      size_t off = ((size_t)kc * HID + coln[n]) * 8;
      bh[n] = *(const short8v*)(Bhi + off);
      bl[n] = *(const short8v*)(Blo + off);
    }

#pragma unroll
    for (int m = 0; m < 4; ++m)
#pragma unroll
      for (int n = 0; n < 4; ++n) {
        acc[m][n] = __builtin_amdgcn_mfma_f32_16x16x32_bf16(ah[m], bh[n], acc[m][n], 0, 0, 0);
        acc[m][n] = __builtin_amdgcn_mfma_f32_16x16x32_bf16(al[m], bh[n], acc[m][n], 0, 0, 0);
        acc[m][n] = __builtin_amdgcn_mfma_f32_16x16x32_bf16(ah[m], bl[n], acc[m][n], 0, 0, 0);
      }

    __syncthreads();
  }

  // C/D layout: col = lane&15, row = (lane>>4)*4 + reg; wave offset wr*64 included
#pragma unroll
  for (int m = 0; m < 4; ++m)
#pragma unroll
    for (int i = 0; i < 4; ++i) {
      int r = row_base + wr * 64 + m * 16 + g * 4 + i;
      if (r < NND) {
#pragma unroll
        for (int n = 0; n < 4; ++n)
          C[(size_t)r * HID + coln[n]] = f2bf_rne(acc[m][n][i]);
      }
    }
}

// ---------------- GEMM2: h2b(bf16) = [hg;hp] @ W2, register-A bf16 -----------
// A rows: plain bf16 x K (hhs hi-only). B keeps hi+lo (2 MFMA per fragment).
// Output node-interleaved bf16: rows [0,NND) -> h2b[r][c],
// rows [NND,2NND) -> h2b[r-NND][64+c].

template<int WR>
__global__ __launch_bounds__(256, 4) void gemm2_split(
    const ushort* __restrict__ As, const ushort* __restrict__ Bhi,
    const ushort* __restrict__ Blo, ushort* __restrict__ C,
    int M, int K, int Nc) {
  const int lane = threadIdx.x & 63;
  const int w = threadIdx.x >> 6;
  const int g = lane >> 4;
  const int l16 = lane & 15;
  const int row_base = blockIdx.x * (WR * 64) + w * 64;

  size_t arow[4];
#pragma unroll
  for (int m = 0; m < 4; ++m) {
    int r = row_base + m * 16 + l16;
    if (r >= M) r = M - 1;
    arow[m] = (size_t)r * K;
  }
  int coln[4];
#pragma unroll
  for (int n = 0; n < 4; ++n) coln[n] = n * 16 + l16;

  f32x4 acc[4][4] = {};

  for (int k0 = 0; k0 < K; k0 += 32) {
    short8v ah[4];
#pragma unroll
    for (int m = 0; m < 4; ++m)
      ah[m] = *(const short8v*)(As + arow[m] + k0 + g * 8);
    short8v bh[4], bl[4];
    const int kc = (k0 >> 3) + g;
#pragma unroll
    for (int n = 0; n < 4; ++n) {
      size_t off = ((size_t)kc * Nc + coln[n]) * 8;
      bh[n] = *(const short8v*)(Bhi + off);
      bl[n] = *(const short8v*)(Blo + off);
    }
#pragma unroll
    for (int m = 0; m < 4; ++m)
#pragma unroll
      for (int n = 0; n < 4; ++n) {
        acc[m][n] = __builtin_amdgcn_mfma_f32_16x16x32_bf16(ah[m], bh[n], acc[m][n], 0, 0, 0);
        acc[m][n] = __builtin_amdgcn_mfma_f32_16x16x32_bf16(ah[m], bl[n], acc[m][n], 0, 0, 0);
      }
  }

#pragma unroll
  for (int m = 0; m < 4; ++m)
#pragma unroll
    for (int i = 0; i < 4; ++i) {
      int r = row_base + m * 16 + g * 4 + i;
      if (r < M) {
#pragma unroll
        for (int n = 0; n < 4; ++n) {
          int c = coln[n];
          size_t o = (r < NND) ? ((size_t)r * 128 + c)
                               : ((size_t)(r - NND) * 128 + 64 + c);
          C[o] = f2bf_rne(acc[m][n][i]);
        }
      }
    }
}

// ---------------- layer-1 aggregation: bf16 gathers, 4 edges in flight -------
// one wave/node; 4 groups x 16 lanes; lane covers feats 8t..8t+7 (ushort8=16B).
// outputs relu(agg+b1) as bf16-RNE rows: hhs[wid] = g, hhs[NND+wid] = p.

__global__ __launch_bounds__(256) void k_agg1(
    const ushort* __restrict__ hlinb, const int* __restrict__ row_ptr,
    const int4* __restrict__ csr,
    const float* __restrict__ dinv_g, const float* __restrict__ dinv_p,
    const float* __restrict__ b1, ushort* __restrict__ hhs) {
  int wid = (blockIdx.x * blockDim.x + threadIdx.x) >> 6;
  int lane = threadIdx.x & 63;
  if (wid >= NND) return;
  const int gp = lane >> 4;
  const int t  = lane & 15;
  float sg = dinv_g[wid]; sg *= sg;
  float sp = dinv_p[wid]; sp *= sp;

  float ag[8] = {}, ap[8] = {};
  if (gp == 0) {
    ushort8v v = *(const ushort8v*)(hlinb + (size_t)wid * HID + 8 * t);
#pragma unroll
    for (int i = 0; i < 8; ++i) {
      float f = bf2f(v[i]);
      ag[i] = f * sg; ap[i] = f * sp;
    }
  }
  int e0 = row_ptr[wid], e1 = row_ptr[wid + 1];
  int k = e0 + gp;
  if (k < e1) {
    int4 rec = csr[k];
    while (true) {
      int kn = k + 4;
      int4 nrec = csr[kn < e1 ? kn : k];      // clamped prefetch
      float wg = __int_as_float(rec.y);
      float wp = __int_as_float(rec.z);
      ushort8v u = *(const ushort8v*)(hlinb + (size_t)rec.x * HID + 8 * t);
#pragma unroll
      for (int i = 0; i < 8; ++i) {
        float f = bf2f(u[i]);
        ag[i] = fmaf(f, wg, ag[i]);
        ap[i] = fmaf(f, wp, ap[i]);
      }
      if (kn >= e1) break;
      k = kn; rec = nrec;
    }
  }
#pragma unroll
  for (int i = 0; i < 8; ++i) {
    ag[i] += __shfl_xor(ag[i], 32); ap[i] += __shfl_xor(ap[i], 32);
    ag[i] += __shfl_xor(ag[i], 16); ap[i] += __shfl_xor(ap[i], 16);
  }

  float bb[8];
  *(float4*)&bb[0] = *(const float4*)(b1 + 8 * t);
  *(float4*)&bb[4] = *(const float4*)(b1 + 8 * t + 4);
  if (gp == 0 || gp == 2) {
    ushort8v outv;
#pragma unroll
    for (int i = 0; i < 8; ++i) {
      float v = (gp == 0) ? fmaxf(ag[i] + bb[i], 0.f) : fmaxf(ap[i] + bb[i], 0.f);
      outv[i] = f2bf_rne(v);
    }
    size_t row = (gp == 0) ? (size_t)wid : (size_t)(NND + wid);
    *(ushort8v*)(hhs + row * HID + 8 * t) = outv;
  }
}

// ---------------- layer-2 aggregation + attention -> emb ---------------------
// h2b node-interleaved bf16 [node][128]: g|p. 4 groups x 16 lanes; within a
// group: t<8 accumulates g feats 8t.., t>=8 accumulates p feats 8(t-8)..

__global__ __launch_bounds__(256) void k_agg2(
    const ushort* __restrict__ h2b, const int* __restrict__ row_ptr,
    const int4* __restrict__ csr,
    const float* __restrict__ dinv_g, const float* __restrict__ dinv_p,
    const float* __restrict__ b2, const float* __restrict__ att_w,
    const float* __restrict__ att_b, float* __restrict__ out_emb) {
  int wid = (blockIdx.x * blockDim.x + threadIdx.x) >> 6;
  int lane = threadIdx.x & 63;
  if (wid >= NND) return;
  const int gp = lane >> 4;
  const int t  = lane & 15;
  const int br = t >> 3;            // 0 = g branch, 1 = p branch
  const int f0 = (t & 7) * 8;       // feature base within branch
  float sg = dinv_g[wid]; sg *= sg;
  float sp = dinv_p[wid]; sp *= sp;
  const float sw = br ? sp : sg;

  float acc[8] = {};
  if (gp == 0) {
    ushort8v v = *(const ushort8v*)(h2b + (size_t)wid * 128 + 8 * t);
#pragma unroll
    for (int i = 0; i < 8; ++i) acc[i] = bf2f(v[i]) * sw;
  }
  int e0 = row_ptr[wid], e1 = row_ptr[wid + 1];
  int k = e0 + gp;
  if (k < e1) {
    int4 rec = csr[k];
    while (true) {
      int kn = k + 4;
      int4 nrec = csr[kn < e1 ? kn : k];
      float w = __int_as_float(br ? rec.z : rec.y);
      ushort8v u = *(const ushort8v*)(h2b + (size_t)rec.x * 128 + 8 * t);
#pragma unroll
      for (int i = 0; i < 8; ++i) acc[i] = fmaf(bf2f(u[i]), w, acc[i]);
      if (kn >= e1) break;
      k = kn; rec = nrec;
    }
  }
#pragma unroll
  for (int i = 0; i < 8; ++i) {
    acc[i] += __shfl_xor(acc[i], 32);
    acc[i] += __shfl_xor(acc[i], 16);
  }

  float bb[8];
  *(float4*)&bb[0] = *(const float4*)(b2 + f0);
  *(float4*)&bb[4] = *(const float4*)(b2 + f0 + 4);
  float v[8];
#pragma unroll
  for (int i = 0; i < 8; ++i) v[i] = acc[i] + bb[i];

  float aw[8];
  *(float4*)&aw[0] = *(const float4*)(att_w + f0);
  *(float4*)&aw[4] = *(const float4*)(att_w + f0 + 4);
  float part = 0.f;
#pragma unroll
  for (int i = 0; i < 8; ++i) part = fmaf(v[i], aw[i], part);
  part += __shfl_xor(part, 4);
  part += __shfl_xor(part, 2);
  part += __shfl_xor(part, 1);
  float other = __shfl_xor(part, 8);
  float ab = att_b[0];
  float lg = (br ? other : part) + ab;
  float lp = (br ? part : other) + ab;
  float mx = fmaxf(lg, lp);
  float eg = expf(lg - mx), ep2 = expf(lp - mx);
  float wsm = eg / (eg + ep2);          // weight of g branch

  float ov[8];
#pragma unroll
  for (int i = 0; i < 8; ++i) ov[i] = __shfl_xor(v[i], 8);
  if (gp == 0 && br == 0) {
    float4* dst = (float4*)(out_emb + (size_t)wid * 64 + f0);
    float4 o0, o1;
    o0.x = wsm * v[0] + (1.f - wsm) * ov[0];
    o0.y = wsm * v[1] + (1.f - wsm) * ov[1];
    o0.z = wsm * v[2] + (1.f - wsm) * ov[2];
    o0.w = wsm * v[3] + (1.f - wsm) * ov[3];
    o1.x = wsm * v[4] + (1.f - wsm) * ov[4];
    o1.y = wsm * v[5] + (1.f - wsm) * ov[5];
    o1.z = wsm * v[6] + (1.f - wsm) * ov[6];
    o1.w = wsm * v[7] + (1.f - wsm) * ov[7];
    dst[0] = o0;
    dst[1] = o1;
  }
}

// ---------------- class + domain heads --------------

__global__ __launch_bounds__(128) void k_head(
    const float* __restrict__ emb,
    const float* __restrict__ cls_w, const float* __restrict__ cls_b,
    const float* __restrict__ dw1, const float* __restrict__ db1,
    const float* __restrict__ dw2, const float* __restrict__ db2,
    float* __restrict__ out_cls, float* __restrict__ out_dom) {
  __shared__ float se[128 * 65];
  const int t = threadIdx.x;
  const int base = blockIdx.x * 128;
  for (int c = 0; c < 64; ++c) {
    int idx = c * 128 + t;
    int nl = idx >> 6, k = idx & 63;
    size_t g = (size_t)base * ENC + idx;
    float v = (g < (size_t)NND * ENC) ? emb[g] : 0.f;
    se[nl * 65 + k] = v;
  }
  __syncthreads();

  int node = base + t;
  float c[NCLS], hd[DOM];
#pragma unroll
  for (int j = 0; j < NCLS; ++j) c[j] = cls_b[j];
#pragma unroll
  for (int j = 0; j < DOM; ++j) hd[j] = db1[j];

  for (int k = 0; k < ENC; ++k) {
    float ev = se[t * 65 + k];
#pragma unroll
    for (int j = 0; j < NCLS; ++j) c[j] += ev * cls_w[k * NCLS + j];
#pragma unroll
    for (int j = 0; j < DOM; ++j) hd[j] += ev * dw1[k * DOM + j];
  }
  float d0 = db2[0], d1 = db2[1];
#pragma unroll
  for (int j = 0; j < DOM; ++j) {
    float hv = fmaxf(hd[j], 0.f);
    d0 += hv * dw2[j * 2];
    d1 += hv * dw2[j * 2 + 1];
  }
  if (node < NND) {
#pragma unroll
    for (int j = 0; j < NCLS; ++j) out_cls[(size_t)node * NCLS + j] = c[j];
    out_dom[(size_t)node * 2]     = d0;
    out_dom[(size_t)node * 2 + 1] = d1;
  }
}

// ---------------- host ----------------

extern "C" void kernel_launch(void* const* d_in, const int* in_sizes, int n_in,
                              void* d_out, int out_size, void* d_ws, size_t ws_size,
                              hipStream_t stream) {
  const float* x     = (const float*)d_in[0];
  const int*   ei    = (const int*)d_in[1];
  const float* ppmi  = (const float*)d_in[2];
  const float* W1    = (const float*)d_in[4];
  const float* b1    = (const float*)d_in[5];
  const float* W2    = (const float*)d_in[6];
  const float* b2    = (const float*)d_in[7];
  const float* att_w = (const float*)d_in[8];
  const float* att_b = (const float*)d_in[9];
  const float* cls_w = (const float*)d_in[10];
  const float* cls_b = (const float*)d_in[11];
  const float* dw1   = (const float*)d_in[12];
  const float* db1   = (const float*)d_in[13];
  const float* dw2   = (const float*)d_in[14];
  const float* db2   = (const float*)d_in[15];

  const int* src = ei;
  const int* dst = ei + NED;

  uintptr_t p = (uintptr_t)d_ws;
  auto alloc = [&](size_t bytes) -> void* {
    void* r = (void*)p;
    p += (bytes + 255) & ~(size_t)255;
    return r;
  };
  unsigned long long* packed = (unsigned long long*)alloc((size_t)NND * 8);
  int*    rank    = (int*)   alloc((size_t)NED * 4);
  int*    row_ptr = (int*)   alloc((size_t)(NND + 1) * 4);
  int*    psum    = (int*)   alloc((size_t)NBS * 4);
  float*  dinv_g  = (float*) alloc((size_t)NND * 4);
  float*  dinv_p  = (float*) alloc((size_t)NND * 4);
  int4*   csr     = (int4*)  alloc((size_t)NED * 16);
  ushort* b1hi    = (ushort*)alloc((size_t)FIN * HID * 2);
  ushort* b1lo    = (ushort*)alloc((size_t)FIN * HID * 2);
  ushort* b2hi    = (ushort*)alloc((size_t)HID * ENC * 2);
  ushort* b2lo    = (ushort*)alloc((size_t)HID * ENC * 2);
  ushort* h2b     = (ushort*)alloc((size_t)NND * HID * 2);        // bf16 h2 pair
  ushort* hhs     = (ushort*)alloc((size_t)2 * NND * HID * 2);    // bf16 hg|hp

  float* out_emb = (float*)d_out;
  float* out_cls = (float*)d_out + (size_t)NND * ENC;
  float* out_dom = (float*)d_out + (size_t)NND * (ENC + NCLS);

  // bf16 h_lin lives in the d_out emb region (NND*128*2B == NND*64*4B exactly);
  // dead before agg2 overwrites the region with emb.
  ushort* h_linb = (ushort*)d_out;

  // ---- graph preprocessing ----
  hipMemsetAsync(packed, 0, (size_t)NND * 8, stream);

  k_deg_rank<<<NED / 256, 256, 0, stream>>>(dst, ppmi, packed, rank);
  k_dinv<<<(NND + 255) / 256, 256, 0, stream>>>(packed, dinv_g, dinv_p);
  k_scan_a<<<NBS, SCAN_BS, 0, stream>>>(packed, psum);
  k_scan_b<<<1, 512, 0, stream>>>(psum);
  k_scan_c<<<NBS, SCAN_BS, 0, stream>>>(packed, psum, row_ptr);
  k_scatter<<<NED / 256, 256, 0, stream>>>(src, dst, ppmi, row_ptr, rank,
                                           dinv_g, dinv_p, csr);

  // ---- weight preconversion (tiny) ----
  k_bprep<HID><<<(FIN * HID + 255) / 256, 256, 0, stream>>>(W1, b1hi, b1lo, FIN);
  k_bprep<ENC><<<(HID * ENC + 255) / 256, 256, 0, stream>>>(W2, b2hi, b2lo, HID);

  // ---- encoder ----
  gemm1_lds<<<(NND + 127) / 128, 256, 0, stream>>>(x, b1hi, b1lo, h_linb);
  k_agg1<<<(NND * 64) / 256, 256, 0, stream>>>(h_linb, row_ptr, csr,
                                               dinv_g, dinv_p, b1, hhs);
  gemm2_split<4><<<(2 * NND + 255) / 256, 256, 0, stream>>>(
      hhs, b2hi, b2lo, h2b, 2 * NND, HID, ENC);
  k_agg2<<<(NND * 64) / 256, 256, 0, stream>>>(h2b, row_ptr, csr,
                                               dinv_g, dinv_p, b2, att_w, att_b, out_emb);

  // ---- heads ----
  k_head<<<(NND + 127) / 128, 128, 0, stream>>>(out_emb, cls_w, cls_b, dw1, db1,
                                                dw2, db2, out_cls, out_dom);
}